// Round 1
// baseline (2179.791 us; speedup 1.0000x reference)
//
#include <hip/hip_runtime.h>
#include <math.h>

#define F 64
#define LDIM 16
#define NRAD 8
#define HID_R 64
#define HID_READ 32
#define NSPEC 10

// l index for each m: m=0 -> l0, m in 1..3 -> l1, m in 4..8 -> l2, m in 9..15 -> l3
__device__ __forceinline__ int l_of_m(int m) {
    return (m == 0) ? 0 : (m < 4) ? 1 : (m < 9) ? 2 : 3;
}

__device__ __forceinline__ float silu(float x) {
    return x / (1.0f + __expf(-x));
}

// ---------------- geometry: r, Y(16), Remb(8) per edge ----------------
__global__ void geo_kernel(const float* __restrict__ vectors,
                           float* __restrict__ Y, float* __restrict__ Remb, int E) {
    int e = blockIdx.x * 256 + threadIdx.x;
    if (e >= E) return;
    float vx = vectors[e * 3 + 0];
    float vy = vectors[e * 3 + 1];
    float vz = vectors[e * 3 + 2];
    float r = sqrtf(vx * vx + vy * vy + vz * vz + 1e-12f);
    float x = vx / r, y = vy / r, z = vz / r;
    float r2 = x * x + y * y + z * z;
    float* Ye = Y + (size_t)e * 16;
    Ye[0]  = 1.0f;
    Ye[1]  = x;
    Ye[2]  = y;
    Ye[3]  = z;
    Ye[4]  = x * y;
    Ye[5]  = y * z;
    Ye[6]  = 3.0f * z * z - r2;
    Ye[7]  = x * z;
    Ye[8]  = x * x - y * y;
    Ye[9]  = y * (3.0f * x * x - y * y);
    Ye[10] = x * y * z;
    Ye[11] = y * (5.0f * z * z - r2);
    Ye[12] = z * (5.0f * z * z - 3.0f * r2);
    Ye[13] = x * (5.0f * z * z - r2);
    Ye[14] = z * (x * x - y * y);
    Ye[15] = x * (x * x - 3.0f * y * y);

    float u = r / 5.0f;
    float env = (u < 1.0f) ? (1.0f - u) * (1.0f - u) * (1.0f + 2.0f * u) : 0.0f;
    float inv = env / (u + 1e-6f);
    const float PI = 3.14159265358979323846f;
#pragma unroll
    for (int k = 1; k <= NRAD; k++) {
        Remb[(size_t)e * NRAD + (k - 1)] = sinf(PI * (float)k * u) * inv;
    }
}

// ---------------- feats init: feats_t[n][m][f], m=0 row = embed ----------------
__global__ void init_feats_kernel(const float* __restrict__ w_embed,
                                  const int* __restrict__ specie,
                                  float* __restrict__ feats_t, int N) {
    int n = blockIdx.x;
    int sp = specie[n];
    for (int i = threadIdx.x; i < F * LDIM; i += 256) {
        int m = i >> 6;
        int f = i & 63;
        feats_t[(size_t)n * (F * LDIM) + i] = (m == 0) ? w_embed[sp * F + f] : 0.0f;
    }
}

// ---------------- edge kernel: radial MLP + message + atomic scatter ----------------
// one wave (64 lanes) per edge; 4 edges per 256-thread block
__global__ void edge_kernel(const float* __restrict__ Y, const float* __restrict__ Remb,
                            const float* __restrict__ feats_t,
                            const int* __restrict__ senders, const int* __restrict__ receivers,
                            const float* __restrict__ w1,   // (8, 64)
                            const float* __restrict__ w2,   // (64, 512)
                            float* __restrict__ agg_t, int E) {
    const int wave = threadIdx.x >> 6;
    const int lane = threadIdx.x & 63;
    const int e = blockIdx.x * 4 + wave;   // grid is exactly E/4, E % 4 == 0

    __shared__ float hbuf[4][64];

    // hidden layer: h[lane] = silu( sum_k Remb[e][k] * w1[k][lane] )
    const float* remb = Remb + (size_t)e * NRAD;
    float acc = 0.0f;
#pragma unroll
    for (int k = 0; k < NRAD; k++) acc += remb[k] * w1[k * F + lane];
    hbuf[wave][lane] = silu(acc);
    __syncthreads();

    // output layer: lane f computes R[f][l][c] for (l,c) flattened 0..7
    float r8[8] = {0.f, 0.f, 0.f, 0.f, 0.f, 0.f, 0.f, 0.f};
    const float* w2base = w2 + lane * 8;
#pragma unroll 8
    for (int j = 0; j < HID_R; j++) {
        float hj = hbuf[wave][j];
        const float4 a = *(const float4*)(w2base + j * 512);
        const float4 b = *(const float4*)(w2base + j * 512 + 4);
        r8[0] += hj * a.x; r8[1] += hj * a.y; r8[2] += hj * a.z; r8[3] += hj * a.w;
        r8[4] += hj * b.x; r8[5] += hj * b.y; r8[6] += hj * b.z; r8[7] += hj * b.w;
    }

    const int snd = senders[e];
    const int rcv = receivers[e];
    const float* fsrc = feats_t + (size_t)snd * (F * LDIM);
    float* adst = agg_t + (size_t)rcv * (F * LDIM);

    const float s0 = fsrc[lane];  // m = 0 row
    const float* Ye = Y + (size_t)e * 16;

#pragma unroll
    for (int m = 0; m < LDIM; m++) {
        const int l = l_of_m(m);
        const float ym = Ye[m];                 // broadcast load
        const float fsm = fsrc[m * F + lane];   // coalesced
        const float val = r8[l * 2 + 0] * s0 * ym + r8[l * 2 + 1] * fsm;
        atomicAdd(adst + m * F + lane, val * 0.25f);   // / sqrt(AVG_NEIGH=16)
    }
}

// ---------------- node kernel, layer 0 ----------------
// one block (256 threads) per node: species_linear + poly scale + readout0
__global__ void node0_kernel(const float* __restrict__ agg_t,
                             const int* __restrict__ specie,
                             const float* __restrict__ w_skip0,   // (S,4,F,F)
                             const float* __restrict__ w_poly0,   // (3,S,F)
                             const float* __restrict__ w_read0,   // (F,1)
                             float* __restrict__ feats_t,
                             float* __restrict__ out, int N) {
    const int n = blockIdx.x;
    __shared__ float aggL[F * LDIM];
    __shared__ float h0L[F];

    const int t = threadIdx.x;
    for (int i = t; i < F * LDIM; i += 256) aggL[i] = agg_t[(size_t)n * (F * LDIM) + i];
    __syncthreads();

    const int sp = specie[n];
    const float* W = w_skip0 + (size_t)sp * 4 * F * F;
    const int g = t & 63;
    const int mb = t >> 6;   // 0..3, handles m = mb*4 .. mb*4+3

    float h[4];
#pragma unroll
    for (int j = 0; j < 4; j++) {
        const int m = mb * 4 + j;
        const int l = l_of_m(m);
        const float* Wl = W + l * (F * F);
        float a = 0.0f;
#pragma unroll 8
        for (int f = 0; f < F; f++) a += aggL[m * F + f] * Wl[f * F + g];
        h[j] = a;
    }
    if (mb == 0) h0L[g] = h[0];   // m = 0
    __syncthreads();

    const float s = h0L[g];
    const float c0 = w_poly0[(0 * NSPEC + sp) * F + g];
    const float c1 = w_poly0[(1 * NSPEC + sp) * F + g];
    const float c2 = w_poly0[(2 * NSPEC + sp) * F + g];
    const float scale = c0 + c1 * s + c2 * s * s;

    float f0val = 0.0f;
#pragma unroll
    for (int j = 0; j < 4; j++) {
        const int m = mb * 4 + j;
        const float fv = h[j] * scale;
        feats_t[(size_t)n * (F * LDIM) + m * F + g] = fv;
        if (m == 0) f0val = fv;
    }

    // readout 0: wave 0 (mb==0) reduces f0val * w_read0
    if (mb == 0) {
        float v = f0val * w_read0[g];
#pragma unroll
        for (int off = 32; off > 0; off >>= 1) v += __shfl_down(v, off);
        if (g == 0) out[(size_t)n * 2 + 0] = v;
    }
}

// ---------------- node kernel, layer 1 ----------------
// only feats2[:, :, 0] is needed downstream -> per node: one 64x64 matvec (sc m=0),
// poly scale on agg m=0 row, then 64->32->1 MLP. One wave per node.
__global__ void node1_kernel(const float* __restrict__ agg_t,
                             const float* __restrict__ feats_t,
                             const int* __restrict__ specie,
                             const float* __restrict__ w_skip1,   // (S,4,F,F)
                             const float* __restrict__ w_poly1,   // (3,S,F)
                             const float* __restrict__ w_mlp1,    // (F, 32)
                             const float* __restrict__ w_mlp2,    // (32, 1)
                             float* __restrict__ out, int N) {
    const int wave = threadIdx.x >> 6;
    const int lane = threadIdx.x & 63;
    const int n = blockIdx.x * 4 + wave;   // grid exactly N/4, N % 4 == 0
    const int sp = specie[n];

    // sc0[lane] = sum_f feats1[n, m=0, f] * W1[l=0][f][lane]
    const float* W0 = w_skip1 + (size_t)sp * 4 * F * F;   // l = 0 block
    const float fv = feats_t[(size_t)n * (F * LDIM) + lane];   // m=0 row, coalesced
    float sc0 = 0.0f;
#pragma unroll 8
    for (int f = 0; f < F; f++) {
        const float ff = __shfl(fv, f);
        sc0 += ff * W0[f * F + lane];
    }

    const float h0 = agg_t[(size_t)n * (F * LDIM) + lane];   // h[n, lane, m=0]
    const float c0 = w_poly1[(0 * NSPEC + sp) * F + lane];
    const float c1 = w_poly1[(1 * NSPEC + sp) * F + lane];
    const float c2 = w_poly1[(2 * NSPEC + sp) * F + lane];
    const float scale = c0 + c1 * h0 + c2 * h0 * h0;
    const float f2 = h0 * scale + sc0;

    // MLP: hid[j] = silu(sum_g f2[g] * w_mlp1[g][j]), j = 0..31 (lanes 0..31)
    float acc = 0.0f;
#pragma unroll 8
    for (int gg = 0; gg < F; gg++) {
        const float fg = __shfl(f2, gg);
        if (lane < HID_READ) acc += fg * w_mlp1[gg * HID_READ + lane];
    }
    float o = 0.0f;
    if (lane < HID_READ) o = silu(acc) * w_mlp2[lane];
#pragma unroll
    for (int off = 32; off > 0; off >>= 1) o += __shfl_down(o, off);
    if (lane == 0) out[(size_t)n * 2 + 1] = o;
}

extern "C" void kernel_launch(void* const* d_in, const int* in_sizes, int n_in,
                              void* d_out, int out_size, void* d_ws, size_t ws_size,
                              hipStream_t stream) {
    const float* vectors  = (const float*)d_in[0];
    const int*   specie   = (const int*)d_in[1];
    const int*   senders  = (const int*)d_in[2];
    const int*   receivers= (const int*)d_in[3];
    const float* w_embed  = (const float*)d_in[4];
    const float* w_r1     = (const float*)d_in[5];   // (2, 8, 64)
    const float* w_r2     = (const float*)d_in[6];   // (2, 64, 512)
    const float* w_skip   = (const float*)d_in[7];   // (2, S, 4, F, F)
    const float* w_poly   = (const float*)d_in[8];   // (2, 3, S, F)
    const float* w_read0  = (const float*)d_in[9];   // (F, 1)
    const float* w_mlp1   = (const float*)d_in[10];  // (F, 32)
    const float* w_mlp2   = (const float*)d_in[11];  // (32, 1)
    float* out = (float*)d_out;

    const int E = in_sizes[0] / 3;   // 160000
    const int N = in_sizes[1];       // 10000

    // workspace layout
    char* ws = (char*)d_ws;
    float* Y       = (float*)ws;                      ws += (size_t)E * 16 * sizeof(float);
    float* Remb    = (float*)ws;                      ws += (size_t)E * NRAD * sizeof(float);
    float* feats_t = (float*)ws;                      ws += (size_t)N * F * LDIM * sizeof(float);
    float* agg_t   = (float*)ws;                      ws += (size_t)N * F * LDIM * sizeof(float);

    const size_t aggBytes = (size_t)N * F * LDIM * sizeof(float);

    geo_kernel<<<(E + 255) / 256, 256, 0, stream>>>(vectors, Y, Remb, E);
    init_feats_kernel<<<N, 256, 0, stream>>>(w_embed, specie, feats_t, N);

    // ---- layer 0 ----
    hipMemsetAsync(agg_t, 0, aggBytes, stream);
    edge_kernel<<<E / 4, 256, 0, stream>>>(Y, Remb, feats_t, senders, receivers,
                                           w_r1 + 0 * NRAD * HID_R,
                                           w_r2 + 0 * HID_R * (F * 8),
                                           agg_t, E);
    node0_kernel<<<N, 256, 0, stream>>>(agg_t, specie,
                                        w_skip + (size_t)0 * NSPEC * 4 * F * F,
                                        w_poly + (size_t)0 * 3 * NSPEC * F,
                                        w_read0, feats_t, out, N);

    // ---- layer 1 ----
    hipMemsetAsync(agg_t, 0, aggBytes, stream);
    edge_kernel<<<E / 4, 256, 0, stream>>>(Y, Remb, feats_t, senders, receivers,
                                           w_r1 + 1 * NRAD * HID_R,
                                           w_r2 + 1 * HID_R * (F * 8),
                                           agg_t, E);
    node1_kernel<<<N / 4, 256, 0, stream>>>(agg_t, feats_t, specie,
                                            w_skip + (size_t)1 * NSPEC * 4 * F * F,
                                            w_poly + (size_t)1 * 3 * NSPEC * F,
                                            w_mlp1, w_mlp2, out, N);
}

// Round 2
// 2173.770 us; speedup vs baseline: 1.0028x; 1.0028x over previous
//
#include <hip/hip_runtime.h>
#include <math.h>

#define F 64
#define LDIM 16
#define NRAD 8
#define HID_R 64
#define HID_READ 32
#define NSPEC 10

typedef __attribute__((ext_vector_type(8))) short short8v;
typedef __attribute__((ext_vector_type(4))) float f32x4;

__device__ __forceinline__ int l_of_m(int m) {
    return (m == 0) ? 0 : (m < 4) ? 1 : (m < 9) ? 2 : 3;
}
__device__ __forceinline__ float silu(float x) { return x / (1.0f + __expf(-x)); }
__device__ __forceinline__ unsigned short bf16bits(float x) {
    unsigned int u = __float_as_uint(x);
    u += 0x7fffu + ((u >> 16) & 1u);   // RNE
    return (unsigned short)(u >> 16);
}

// =================== geometry + hidden activations ===================
// per edge: Y[16], Remb[8] (for fallback), H[2][64] bf16
__global__ void geo_h_kernel(const float* __restrict__ vectors,
                             const float* __restrict__ w_r1,   // (2,8,64)
                             float* __restrict__ Y, float* __restrict__ Remb,
                             unsigned short* __restrict__ Hb,  // (2,E,64) bf16
                             int E, int writeH) {
    int e = blockIdx.x * 256 + threadIdx.x;
    if (e >= E) return;
    float vx = vectors[e * 3 + 0];
    float vy = vectors[e * 3 + 1];
    float vz = vectors[e * 3 + 2];
    float r = sqrtf(vx * vx + vy * vy + vz * vz + 1e-12f);
    float x = vx / r, y = vy / r, z = vz / r;
    float r2 = x * x + y * y + z * z;
    float* Ye = Y + (size_t)e * 16;
    Ye[0]  = 1.0f;  Ye[1] = x;  Ye[2] = y;  Ye[3] = z;
    Ye[4]  = x * y; Ye[5] = y * z; Ye[6] = 3.0f * z * z - r2; Ye[7] = x * z;
    Ye[8]  = x * x - y * y;
    Ye[9]  = y * (3.0f * x * x - y * y);
    Ye[10] = x * y * z;
    Ye[11] = y * (5.0f * z * z - r2);
    Ye[12] = z * (5.0f * z * z - 3.0f * r2);
    Ye[13] = x * (5.0f * z * z - r2);
    Ye[14] = z * (x * x - y * y);
    Ye[15] = x * (x * x - 3.0f * y * y);

    float u = r / 5.0f;
    float env = (u < 1.0f) ? (1.0f - u) * (1.0f - u) * (1.0f + 2.0f * u) : 0.0f;
    float inv = env / (u + 1e-6f);
    const float PI = 3.14159265358979323846f;
    float remb[NRAD];
#pragma unroll
    for (int k = 1; k <= NRAD; k++) {
        remb[k - 1] = sinf(PI * (float)k * u) * inv;
        Remb[(size_t)e * NRAD + (k - 1)] = remb[k - 1];
    }
    if (!writeH) return;

    for (int i = 0; i < 2; i++) {
        const float* w1 = w_r1 + (size_t)i * NRAD * HID_R;
        float h[HID_R];
#pragma unroll
        for (int j = 0; j < HID_R; j++) {
            float a = 0.0f;
#pragma unroll
            for (int k = 0; k < NRAD; k++) a += remb[k] * w1[k * HID_R + j];
            h[j] = silu(a);
        }
        unsigned int* dst = (unsigned int*)(Hb + ((size_t)i * E + e) * HID_R);
#pragma unroll
        for (int w = 0; w < 32; w++) {
            unsigned int lo = bf16bits(h[2 * w]);
            unsigned int hi = bf16bits(h[2 * w + 1]);
            dst[w] = lo | (hi << 16);
        }
    }
}

// =================== w2 -> MFMA B-fragment layout, bf16 ===================
// w2f[layer][ct][ks][lane][j] = bf16( w_r2[layer][ ks*32+(lane>>4)*8+j ][ ct*16+(lane&15) ] )
__global__ void conv_w2_kernel(const float* __restrict__ w_r2,
                               unsigned short* __restrict__ w2f) {
    int layer = blockIdx.x;
    const float* src = w_r2 + (size_t)layer * HID_R * 512;
    unsigned short* dst = w2f + (size_t)layer * 32768;
    for (int idx = threadIdx.x; idx < 32768; idx += 256) {
        int j    = idx & 7;
        int lane = (idx >> 3) & 63;
        int ks   = (idx >> 9) & 1;
        int ct   = idx >> 10;
        int k    = ks * 32 + (lane >> 4) * 8 + j;
        int col  = ct * 16 + (lane & 15);
        dst[idx] = bf16bits(src[k * 512 + col]);
    }
}

// =================== CSR build ===================
__global__ void hist_kernel(const int* __restrict__ receivers, int* __restrict__ cnt, int E) {
    int e = blockIdx.x * 256 + threadIdx.x;
    if (e < E) atomicAdd(&cnt[receivers[e]], 1);
}

__global__ void scan_kernel(const int* __restrict__ cnt, int* __restrict__ offs, int N) {
    __shared__ int buf[256];
    __shared__ int carry;
    int t = threadIdx.x;
    if (t == 0) carry = 0;
    __syncthreads();
    for (int base = 0; base < N; base += 256) {
        int v = (base + t < N) ? cnt[base + t] : 0;
        buf[t] = v;
        __syncthreads();
#pragma unroll
        for (int off = 1; off < 256; off <<= 1) {
            int x = (t >= off) ? buf[t - off] : 0;
            __syncthreads();
            buf[t] += x;
            __syncthreads();
        }
        if (base + t < N) offs[base + t] = carry + buf[t] - v;   // exclusive
        __syncthreads();
        if (t == 0) carry += buf[255];
        __syncthreads();
    }
    if (t == 0) offs[N] = carry;
}

__global__ void scatter_kernel(const int* __restrict__ receivers,
                               const int* __restrict__ offs, int* __restrict__ cur,
                               int* __restrict__ eidx, int E) {
    int e = blockIdx.x * 256 + threadIdx.x;
    if (e >= E) return;
    int r = receivers[e];
    int pos = atomicAdd(&cur[r], 1);
    eidx[offs[r] + pos] = e;
}

// =================== feats init ===================
__global__ void init_feats_kernel(const float* __restrict__ w_embed,
                                  const int* __restrict__ specie,
                                  float* __restrict__ feats_t, int N) {
    int n = blockIdx.x;
    int sp = specie[n];
    for (int i = threadIdx.x; i < F * LDIM; i += 256) {
        int m = i >> 6;
        int f = i & 63;
        feats_t[(size_t)n * (F * LDIM) + i] = (m == 0) ? w_embed[sp * F + f] : 0.0f;
    }
}

// =================== R GEMM: R[E,512] = Hb[E,64] @ w2[64,512], bf16 MFMA ===================
// block = 256 thr = 4 waves; block tile = 32 edges x 512 cols
// wave (w&1): edge-subtile of 16; (w>>1): column half (16 ct-tiles of 16)
__global__ void rgemm_kernel(const unsigned short* __restrict__ Hb,  // (E,64) bf16
                             const unsigned short* __restrict__ w2f, // frag layout, 32768
                             float* __restrict__ R, int E) {
    const int wave = threadIdx.x >> 6;
    const int lane = threadIdx.x & 63;
    const int e0 = blockIdx.x * 32 + (wave & 1) * 16;
    const int chalf = wave >> 1;
    const int lo = lane & 15, hi = lane >> 4;

    const short8v a0 = *(const short8v*)(Hb + (size_t)(e0 + lo) * 64 + hi * 8);
    const short8v a1 = *(const short8v*)(Hb + (size_t)(e0 + lo) * 64 + 32 + hi * 8);

    f32x4 acc[16];
#pragma unroll
    for (int i = 0; i < 16; i++) acc[i] = (f32x4)(0.0f);

#pragma unroll
    for (int t = 0; t < 16; t++) {
        const int ct = chalf * 16 + t;
        const short8v b0 = *(const short8v*)(w2f + ct * 1024 + lane * 8);
        const short8v b1 = *(const short8v*)(w2f + ct * 1024 + 512 + lane * 8);
        acc[t] = __builtin_amdgcn_mfma_f32_16x16x32_bf16(a0, b0, acc[t], 0, 0, 0);
        acc[t] = __builtin_amdgcn_mfma_f32_16x16x32_bf16(a1, b1, acc[t], 0, 0, 0);
    }

    // C mapping: edge-row = hi*4 + r, col = ct*16 + lo
#pragma unroll
    for (int t = 0; t < 16; t++) {
        const int ct = chalf * 16 + t;
        float* dst = R + (size_t)(e0 + hi * 4) * 512 + ct * 16 + lo;
#pragma unroll
        for (int r = 0; r < 4; r++) dst[(size_t)r * 512] = acc[t][r];
    }
}

// =================== gather: one wave per node, CSR in-edges ===================
__global__ void gather_kernel(const float* __restrict__ R, const float* __restrict__ Y,
                              const float* __restrict__ feats,
                              const int* __restrict__ senders,
                              const int* __restrict__ offs, const int* __restrict__ eidx,
                              float* __restrict__ agg, int N) {
    const int wave = threadIdx.x >> 6;
    const int lane = threadIdx.x & 63;
    const int n = blockIdx.x * 4 + wave;
    const int t0 = offs[n], t1 = offs[n + 1];

    float acc[LDIM];
#pragma unroll
    for (int m = 0; m < LDIM; m++) acc[m] = 0.0f;

    for (int t = t0; t < t1; t++) {
        const int e = eidx[t];
        const float4 ra = *(const float4*)(R + (size_t)e * 512 + lane * 8);
        const float4 rb = *(const float4*)(R + (size_t)e * 512 + lane * 8 + 4);
        const float r8[8] = {ra.x, ra.y, ra.z, ra.w, rb.x, rb.y, rb.z, rb.w};
        const int snd = senders[e];
        const float* fs = feats + (size_t)snd * (F * LDIM);
        const float* Ye = Y + (size_t)e * 16;
        const float s0 = fs[lane];
#pragma unroll
        for (int m = 0; m < LDIM; m++) {
            const int l = l_of_m(m);
            acc[m] += r8[l * 2] * s0 * Ye[m] + r8[l * 2 + 1] * fs[m * F + lane];
        }
    }
#pragma unroll
    for (int m = 0; m < LDIM; m++)
        agg[(size_t)n * (F * LDIM) + m * F + lane] = acc[m] * 0.25f;
}

// =================== node kernels (unchanged, verified) ===================
__global__ void node0_kernel(const float* __restrict__ agg_t,
                             const int* __restrict__ specie,
                             const float* __restrict__ w_skip0,
                             const float* __restrict__ w_poly0,
                             const float* __restrict__ w_read0,
                             float* __restrict__ feats_t,
                             float* __restrict__ out, int N) {
    const int n = blockIdx.x;
    __shared__ float aggL[F * LDIM];
    __shared__ float h0L[F];
    const int t = threadIdx.x;
    for (int i = t; i < F * LDIM; i += 256) aggL[i] = agg_t[(size_t)n * (F * LDIM) + i];
    __syncthreads();
    const int sp = specie[n];
    const float* W = w_skip0 + (size_t)sp * 4 * F * F;
    const int g = t & 63;
    const int mb = t >> 6;
    float h[4];
#pragma unroll
    for (int j = 0; j < 4; j++) {
        const int m = mb * 4 + j;
        const int l = l_of_m(m);
        const float* Wl = W + l * (F * F);
        float a = 0.0f;
#pragma unroll 8
        for (int f = 0; f < F; f++) a += aggL[m * F + f] * Wl[f * F + g];
        h[j] = a;
    }
    if (mb == 0) h0L[g] = h[0];
    __syncthreads();
    const float s = h0L[g];
    const float c0 = w_poly0[(0 * NSPEC + sp) * F + g];
    const float c1 = w_poly0[(1 * NSPEC + sp) * F + g];
    const float c2 = w_poly0[(2 * NSPEC + sp) * F + g];
    const float scale = c0 + c1 * s + c2 * s * s;
    float f0val = 0.0f;
#pragma unroll
    for (int j = 0; j < 4; j++) {
        const int m = mb * 4 + j;
        const float fv = h[j] * scale;
        feats_t[(size_t)n * (F * LDIM) + m * F + g] = fv;
        if (m == 0) f0val = fv;
    }
    if (mb == 0) {
        float v = f0val * w_read0[g];
#pragma unroll
        for (int off = 32; off > 0; off >>= 1) v += __shfl_down(v, off);
        if (g == 0) out[(size_t)n * 2 + 0] = v;
    }
}

__global__ void node1_kernel(const float* __restrict__ agg_t,
                             const float* __restrict__ feats_t,
                             const int* __restrict__ specie,
                             const float* __restrict__ w_skip1,
                             const float* __restrict__ w_poly1,
                             const float* __restrict__ w_mlp1,
                             const float* __restrict__ w_mlp2,
                             float* __restrict__ out, int N) {
    const int wave = threadIdx.x >> 6;
    const int lane = threadIdx.x & 63;
    const int n = blockIdx.x * 4 + wave;
    const int sp = specie[n];
    const float* W0 = w_skip1 + (size_t)sp * 4 * F * F;
    const float fv = feats_t[(size_t)n * (F * LDIM) + lane];
    float sc0 = 0.0f;
#pragma unroll 8
    for (int f = 0; f < F; f++) {
        const float ff = __shfl(fv, f);
        sc0 += ff * W0[f * F + lane];
    }
    const float h0 = agg_t[(size_t)n * (F * LDIM) + lane];
    const float c0 = w_poly1[(0 * NSPEC + sp) * F + lane];
    const float c1 = w_poly1[(1 * NSPEC + sp) * F + lane];
    const float c2 = w_poly1[(2 * NSPEC + sp) * F + lane];
    const float scale = c0 + c1 * h0 + c2 * h0 * h0;
    const float f2 = h0 * scale + sc0;
    float acc = 0.0f;
#pragma unroll 8
    for (int gg = 0; gg < F; gg++) {
        const float fg = __shfl(f2, gg);
        if (lane < HID_READ) acc += fg * w_mlp1[gg * HID_READ + lane];
    }
    float o = 0.0f;
    if (lane < HID_READ) o = silu(acc) * w_mlp2[lane];
#pragma unroll
    for (int off = 32; off > 0; off >>= 1) o += __shfl_down(o, off);
    if (lane == 0) out[(size_t)n * 2 + 1] = o;
}

// =================== fallback (round-1, known-passing) edge kernel ===================
__global__ void edge_kernel(const float* __restrict__ Y, const float* __restrict__ Remb,
                            const float* __restrict__ feats_t,
                            const int* __restrict__ senders, const int* __restrict__ receivers,
                            const float* __restrict__ w1, const float* __restrict__ w2,
                            float* __restrict__ agg_t, int E) {
    const int wave = threadIdx.x >> 6;
    const int lane = threadIdx.x & 63;
    const int e = blockIdx.x * 4 + wave;
    __shared__ float hbuf[4][64];
    const float* remb = Remb + (size_t)e * NRAD;
    float acc = 0.0f;
#pragma unroll
    for (int k = 0; k < NRAD; k++) acc += remb[k] * w1[k * F + lane];
    hbuf[wave][lane] = silu(acc);
    __syncthreads();
    float r8[8] = {0.f, 0.f, 0.f, 0.f, 0.f, 0.f, 0.f, 0.f};
    const float* w2base = w2 + lane * 8;
#pragma unroll 8
    for (int j = 0; j < HID_R; j++) {
        float hj = hbuf[wave][j];
        const float4 a = *(const float4*)(w2base + j * 512);
        const float4 b = *(const float4*)(w2base + j * 512 + 4);
        r8[0] += hj * a.x; r8[1] += hj * a.y; r8[2] += hj * a.z; r8[3] += hj * a.w;
        r8[4] += hj * b.x; r8[5] += hj * b.y; r8[6] += hj * b.z; r8[7] += hj * b.w;
    }
    const int snd = senders[e];
    const int rcv = receivers[e];
    const float* fsrc = feats_t + (size_t)snd * (F * LDIM);
    float* adst = agg_t + (size_t)rcv * (F * LDIM);
    const float s0 = fsrc[lane];
    const float* Ye = Y + (size_t)e * 16;
#pragma unroll
    for (int m = 0; m < LDIM; m++) {
        const int l = l_of_m(m);
        const float ym = Ye[m];
        const float fsm = fsrc[m * F + lane];
        const float val = r8[l * 2 + 0] * s0 * ym + r8[l * 2 + 1] * fsm;
        atomicAdd(adst + m * F + lane, val * 0.25f);
    }
}

extern "C" void kernel_launch(void* const* d_in, const int* in_sizes, int n_in,
                              void* d_out, int out_size, void* d_ws, size_t ws_size,
                              hipStream_t stream) {
    const float* vectors   = (const float*)d_in[0];
    const int*   specie    = (const int*)d_in[1];
    const int*   senders   = (const int*)d_in[2];
    const int*   receivers = (const int*)d_in[3];
    const float* w_embed   = (const float*)d_in[4];
    const float* w_r1      = (const float*)d_in[5];
    const float* w_r2      = (const float*)d_in[6];
    const float* w_skip    = (const float*)d_in[7];
    const float* w_poly    = (const float*)d_in[8];
    const float* w_read0   = (const float*)d_in[9];
    const float* w_mlp1    = (const float*)d_in[10];
    const float* w_mlp2    = (const float*)d_in[11];
    float* out = (float*)d_out;

    const int E = in_sizes[0] / 3;
    const int N = in_sizes[1];

    // ---- workspace layout ----
    char* ws = (char*)d_ws;
    char* base = ws;
    float* Y      = (float*)ws;  ws += (size_t)E * 16 * sizeof(float);
    float* Remb   = (float*)ws;  ws += (size_t)E * NRAD * sizeof(float);
    float* feats  = (float*)ws;  ws += (size_t)N * F * LDIM * sizeof(float);
    float* agg    = (float*)ws;  ws += (size_t)N * F * LDIM * sizeof(float);
    unsigned short* Hb  = (unsigned short*)ws; ws += (size_t)2 * E * 64 * sizeof(unsigned short);
    float* R      = (float*)ws;  ws += (size_t)E * 512 * sizeof(float);
    int* cnt      = (int*)ws;    ws += ((size_t)N * 4 + 15) & ~15ull;
    int* cur      = (int*)ws;    ws += ((size_t)N * 4 + 15) & ~15ull;
    int* offs     = (int*)ws;    ws += ((size_t)(N + 1) * 4 + 15) & ~15ull;
    int* eidx     = (int*)ws;    ws += (size_t)E * sizeof(int);
    unsigned short* w2f = (unsigned short*)ws; ws += (size_t)2 * 32768 * sizeof(unsigned short);
    const size_t need = (size_t)(ws - base);

    const size_t aggBytes = (size_t)N * F * LDIM * sizeof(float);

    if (ws_size >= need) {
        // =========== main path: MFMA R-GEMM + CSR gather ===========
        geo_h_kernel<<<(E + 255) / 256, 256, 0, stream>>>(vectors, w_r1, Y, Remb, Hb, E, 1);
        conv_w2_kernel<<<2, 256, 0, stream>>>(w_r2, w2f);
        hipMemsetAsync(cnt, 0, (size_t)N * 4, stream);
        hipMemsetAsync(cur, 0, (size_t)N * 4, stream);
        hist_kernel<<<(E + 255) / 256, 256, 0, stream>>>(receivers, cnt, E);
        scan_kernel<<<1, 256, 0, stream>>>(cnt, offs, N);
        scatter_kernel<<<(E + 255) / 256, 256, 0, stream>>>(receivers, offs, cur, eidx, E);
        init_feats_kernel<<<N, 256, 0, stream>>>(w_embed, specie, feats, N);

        // layer 0
        rgemm_kernel<<<E / 32, 256, 0, stream>>>(Hb, w2f, R, E);
        gather_kernel<<<N / 4, 256, 0, stream>>>(R, Y, feats, senders, offs, eidx, agg, N);
        node0_kernel<<<N, 256, 0, stream>>>(agg, specie,
                                            w_skip + (size_t)0 * NSPEC * 4 * F * F,
                                            w_poly + (size_t)0 * 3 * NSPEC * F,
                                            w_read0, feats, out, N);
        // layer 1
        rgemm_kernel<<<E / 32, 256, 0, stream>>>(Hb + (size_t)E * 64, w2f + 32768, R, E);
        gather_kernel<<<N / 4, 256, 0, stream>>>(R, Y, feats, senders, offs, eidx, agg, N);
        node1_kernel<<<N / 4, 256, 0, stream>>>(agg, feats, specie,
                                                w_skip + (size_t)1 * NSPEC * 4 * F * F,
                                                w_poly + (size_t)1 * 3 * NSPEC * F,
                                                w_mlp1, w_mlp2, out, N);
    } else {
        // =========== fallback: round-1 atomic path ===========
        geo_h_kernel<<<(E + 255) / 256, 256, 0, stream>>>(vectors, w_r1, Y, Remb, Hb, E, 0);
        init_feats_kernel<<<N, 256, 0, stream>>>(w_embed, specie, feats, N);
        hipMemsetAsync(agg, 0, aggBytes, stream);
        edge_kernel<<<E / 4, 256, 0, stream>>>(Y, Remb, feats, senders, receivers,
                                               w_r1, w_r2, agg, E);
        node0_kernel<<<N, 256, 0, stream>>>(agg, specie,
                                            w_skip + (size_t)0 * NSPEC * 4 * F * F,
                                            w_poly + (size_t)0 * 3 * NSPEC * F,
                                            w_read0, feats, out, N);
        hipMemsetAsync(agg, 0, aggBytes, stream);
        edge_kernel<<<E / 4, 256, 0, stream>>>(Y, Remb, feats, senders, receivers,
                                               w_r1 + NRAD * HID_R, w_r2 + HID_R * 512,
                                               agg, E);
        node1_kernel<<<N / 4, 256, 0, stream>>>(agg, feats, specie,
                                                w_skip + (size_t)1 * NSPEC * 4 * F * F,
                                                w_poly + (size_t)1 * 3 * NSPEC * F,
                                                w_mlp1, w_mlp2, out, N);
    }
}

// Round 3
// 849.426 us; speedup vs baseline: 2.5662x; 2.5591x over previous
//
#include <hip/hip_runtime.h>
#include <math.h>

#define F 64
#define LDIM 16
#define NRAD 8
#define HID_R 64
#define HID_READ 32
#define NSPEC 10

typedef __attribute__((ext_vector_type(8))) short short8v;
typedef __attribute__((ext_vector_type(4))) float f32x4;

__device__ __forceinline__ int l_of_m(int m) {
    return (m == 0) ? 0 : (m < 4) ? 1 : (m < 9) ? 2 : 3;
}
__device__ __forceinline__ float silu(float x) { return x / (1.0f + __expf(-x)); }
__device__ __forceinline__ unsigned short bf16bits(float x) {
    unsigned int u = __float_as_uint(x);
    u += 0x7fffu + ((u >> 16) & 1u);   // RNE
    return (unsigned short)(u >> 16);
}

__device__ __forceinline__ void geo_core(const float* __restrict__ vectors, int e,
                                         float* Ye_out, float* remb_out) {
    float vx = vectors[e * 3 + 0];
    float vy = vectors[e * 3 + 1];
    float vz = vectors[e * 3 + 2];
    float r = sqrtf(vx * vx + vy * vy + vz * vz + 1e-12f);
    float x = vx / r, y = vy / r, z = vz / r;
    float r2 = x * x + y * y + z * z;
    Ye_out[0]  = 1.0f;  Ye_out[1] = x;  Ye_out[2] = y;  Ye_out[3] = z;
    Ye_out[4]  = x * y; Ye_out[5] = y * z; Ye_out[6] = 3.0f * z * z - r2; Ye_out[7] = x * z;
    Ye_out[8]  = x * x - y * y;
    Ye_out[9]  = y * (3.0f * x * x - y * y);
    Ye_out[10] = x * y * z;
    Ye_out[11] = y * (5.0f * z * z - r2);
    Ye_out[12] = z * (5.0f * z * z - 3.0f * r2);
    Ye_out[13] = x * (5.0f * z * z - r2);
    Ye_out[14] = z * (x * x - y * y);
    Ye_out[15] = x * (x * x - 3.0f * y * y);
    float u = r / 5.0f;
    float env = (u < 1.0f) ? (1.0f - u) * (1.0f - u) * (1.0f + 2.0f * u) : 0.0f;
    float inv = env / (u + 1e-6f);
    const float PI = 3.14159265358979323846f;
#pragma unroll
    for (int k = 1; k <= NRAD; k++) remb_out[k - 1] = sinf(PI * (float)k * u) * inv;
}

// ---------- fast path: Y (layer 0 only) + one layer's H (bf16) ----------
__global__ void geo_h_layer_kernel(const float* __restrict__ vectors,
                                   const float* __restrict__ w1,   // (8,64) for this layer
                                   float* __restrict__ Y,
                                   unsigned short* __restrict__ Hb, // (E,64) bf16
                                   int E, int writeY) {
    int e = blockIdx.x * 256 + threadIdx.x;
    if (e >= E) return;
    float ye[16], remb[NRAD];
    geo_core(vectors, e, ye, remb);
    if (writeY) {
        float4* Yd = (float4*)(Y + (size_t)e * 16);
        Yd[0] = make_float4(ye[0], ye[1], ye[2], ye[3]);
        Yd[1] = make_float4(ye[4], ye[5], ye[6], ye[7]);
        Yd[2] = make_float4(ye[8], ye[9], ye[10], ye[11]);
        Yd[3] = make_float4(ye[12], ye[13], ye[14], ye[15]);
    }
    float h[HID_R];
#pragma unroll
    for (int j = 0; j < HID_R; j++) {
        float a = 0.0f;
#pragma unroll
        for (int k = 0; k < NRAD; k++) a += remb[k] * w1[k * HID_R + j];
        h[j] = silu(a);
    }
    unsigned int* dst = (unsigned int*)(Hb + (size_t)e * HID_R);
#pragma unroll
    for (int w = 0; w < 32; w++) {
        unsigned int lo = bf16bits(h[2 * w]);
        unsigned int hi = bf16bits(h[2 * w + 1]);
        dst[w] = lo | (hi << 16);
    }
}

// ---------- fallback geo: Y + Remb ----------
__global__ void geo_kernel(const float* __restrict__ vectors,
                           float* __restrict__ Y, float* __restrict__ Remb, int E) {
    int e = blockIdx.x * 256 + threadIdx.x;
    if (e >= E) return;
    float ye[16], remb[NRAD];
    geo_core(vectors, e, ye, remb);
#pragma unroll
    for (int m = 0; m < 16; m++) Y[(size_t)e * 16 + m] = ye[m];
#pragma unroll
    for (int k = 0; k < NRAD; k++) Remb[(size_t)e * NRAD + k] = remb[k];
}

// ---------- w2 -> MFMA B-fragment layout, bf16 ----------
// w2f[layer][ct*1024 + ks*512 + lane*8 + j] = bf16( w2[ks*32+(lane>>4)*8+j][ct*16+(lane&15)] )
__global__ void conv_w2_kernel(const float* __restrict__ w_r2,
                               unsigned short* __restrict__ w2f) {
    int layer = blockIdx.x;
    const float* src = w_r2 + (size_t)layer * HID_R * 512;
    unsigned short* dst = w2f + (size_t)layer * 32768;
    for (int idx = threadIdx.x; idx < 32768; idx += 256) {
        int j    = idx & 7;
        int lane = (idx >> 3) & 63;
        int ks   = (idx >> 9) & 1;
        int ct   = idx >> 10;
        int k    = ks * 32 + (lane >> 4) * 8 + j;
        int col  = ct * 16 + (lane & 15);
        dst[idx] = bf16bits(src[k * 512 + col]);
    }
}

// ---------- CSR build ----------
__global__ void hist_kernel(const int* __restrict__ receivers, int* __restrict__ cnt, int E) {
    int e = blockIdx.x * 256 + threadIdx.x;
    if (e < E) atomicAdd(&cnt[receivers[e]], 1);
}

__global__ void scan_kernel(const int* __restrict__ cnt, int* __restrict__ offs, int N) {
    __shared__ int buf[256];
    __shared__ int carry;
    int t = threadIdx.x;
    if (t == 0) carry = 0;
    __syncthreads();
    for (int base = 0; base < N; base += 256) {
        int v = (base + t < N) ? cnt[base + t] : 0;
        buf[t] = v;
        __syncthreads();
#pragma unroll
        for (int off = 1; off < 256; off <<= 1) {
            int x = (t >= off) ? buf[t - off] : 0;
            __syncthreads();
            buf[t] += x;
            __syncthreads();
        }
        if (base + t < N) offs[base + t] = carry + buf[t] - v;   // exclusive
        __syncthreads();
        if (t == 0) carry += buf[255];
        __syncthreads();
    }
    if (t == 0) offs[N] = carry;
}

__global__ void scatter_kernel(const int* __restrict__ receivers,
                               const int* __restrict__ senders,
                               const int* __restrict__ offs, int* __restrict__ cur,
                               int* __restrict__ eidx, int* __restrict__ snd_csr, int E) {
    int e = blockIdx.x * 256 + threadIdx.x;
    if (e >= E) return;
    int r = receivers[e];
    int pos = atomicAdd(&cur[r], 1);
    int t = offs[r] + pos;
    eidx[t] = e;
    snd_csr[t] = senders[e];
}

// ---------- feats init ----------
__global__ void init_feats_kernel(const float* __restrict__ w_embed,
                                  const int* __restrict__ specie,
                                  float* __restrict__ feats_t, int N) {
    int n = blockIdx.x;
    int sp = specie[n];
    for (int i = threadIdx.x; i < F * LDIM; i += 256) {
        int m = i >> 6;
        int f = i & 63;
        feats_t[(size_t)n * (F * LDIM) + i] = (m == 0) ? w_embed[sp * F + f] : 0.0f;
    }
}

// ---------- R GEMM over a CSR-position chunk ----------
// R_chunk[t - t0][512] = H[eidx[t]] @ w2   (bf16 MFMA, fp32 out)
// block = 4 waves; wave&1 -> 16-edge subtile, wave>>1 -> column half
__global__ void rgemm_chunk_kernel(const unsigned short* __restrict__ Hb,
                                   const unsigned short* __restrict__ w2f, // this layer
                                   const int* __restrict__ eidx,
                                   float* __restrict__ R, int t0, int t1) {
    const int wave = threadIdx.x >> 6;
    const int lane = threadIdx.x & 63;
    const int lo = lane & 15, hi = lane >> 4;
    const int g = blockIdx.x * 2 + (wave & 1);    // 16-edge group within chunk
    const int chalf = wave >> 1;

    const int pos = t0 + g * 16 + lo;
    const int eid = eidx[(pos < t1) ? pos : (t1 - 1)];
    const short8v a0 = *(const short8v*)(Hb + (size_t)eid * 64 + hi * 8);
    const short8v a1 = *(const short8v*)(Hb + (size_t)eid * 64 + 32 + hi * 8);

    f32x4 acc[16];
#pragma unroll
    for (int i = 0; i < 16; i++) acc[i] = (f32x4)(0.0f);

#pragma unroll
    for (int t = 0; t < 16; t++) {
        const int ct = chalf * 16 + t;
        const short8v b0 = *(const short8v*)(w2f + ct * 1024 + lane * 8);
        const short8v b1 = *(const short8v*)(w2f + ct * 1024 + 512 + lane * 8);
        acc[t] = __builtin_amdgcn_mfma_f32_16x16x32_bf16(a0, b0, acc[t], 0, 0, 0);
        acc[t] = __builtin_amdgcn_mfma_f32_16x16x32_bf16(a1, b1, acc[t], 0, 0, 0);
    }

    // C layout: col = ct*16 + lo, row(edge within group) = hi*4 + r
#pragma unroll
    for (int t = 0; t < 16; t++) {
        const int ct = chalf * 16 + t;
#pragma unroll
        for (int r = 0; r < 4; r++) {
            const int row = g * 16 + hi * 4 + r;     // chunk-relative
            if (t0 + row < t1)
                R[(size_t)row * 512 + ct * 16 + lo] = acc[t][r];
        }
    }
}

// ---------- gather over a CSR-position chunk: one wave per node, += into agg ----------
__global__ void gather_chunk_kernel(const float* __restrict__ R,
                                    const float* __restrict__ Y,
                                    const float* __restrict__ feats,
                                    const int* __restrict__ snd_csr,
                                    const int* __restrict__ eidx,
                                    const int* __restrict__ offs,
                                    float* __restrict__ agg,
                                    int N, int t0, int t1) {
    const int wave = threadIdx.x >> 6;
    const int lane = threadIdx.x & 63;
    const int n = blockIdx.x * 4 + wave;
    if (n >= N) return;
    const int s = offs[n], e = offs[n + 1];
    const int a = (s > t0) ? s : t0;
    const int b = (e < t1) ? e : t1;
    if (a >= b) return;

    float acc[LDIM];
#pragma unroll
    for (int m = 0; m < LDIM; m++) acc[m] = 0.0f;

    for (int t = a; t < b; t++) {
        const float* Rrow = R + (size_t)(t - t0) * 512;
        const float4 ra = *(const float4*)(Rrow + lane * 8);
        const float4 rb = *(const float4*)(Rrow + lane * 8 + 4);
        const float r8[8] = {ra.x, ra.y, ra.z, ra.w, rb.x, rb.y, rb.z, rb.w};
        const int snd = snd_csr[t];
        const int eid = eidx[t];
        const float* fs = feats + (size_t)snd * (F * LDIM);
        const float* Ye = Y + (size_t)eid * 16;
        const float s0 = fs[lane];
#pragma unroll
        for (int m = 0; m < LDIM; m++) {
            const int l = l_of_m(m);
            acc[m] += r8[l * 2] * s0 * Ye[m] + r8[l * 2 + 1] * fs[m * F + lane];
        }
    }
#pragma unroll
    for (int m = 0; m < LDIM; m++) {
        const size_t o = (size_t)n * (F * LDIM) + m * F + lane;
        agg[o] += acc[m] * 0.25f;
    }
}

// ---------- node kernels (verified) ----------
__global__ void node0_kernel(const float* __restrict__ agg_t,
                             const int* __restrict__ specie,
                             const float* __restrict__ w_skip0,
                             const float* __restrict__ w_poly0,
                             const float* __restrict__ w_read0,
                             float* __restrict__ feats_t,
                             float* __restrict__ out, int N) {
    const int n = blockIdx.x;
    __shared__ float aggL[F * LDIM];
    __shared__ float h0L[F];
    const int t = threadIdx.x;
    for (int i = t; i < F * LDIM; i += 256) aggL[i] = agg_t[(size_t)n * (F * LDIM) + i];
    __syncthreads();
    const int sp = specie[n];
    const float* W = w_skip0 + (size_t)sp * 4 * F * F;
    const int g = t & 63;
    const int mb = t >> 6;
    float h[4];
#pragma unroll
    for (int j = 0; j < 4; j++) {
        const int m = mb * 4 + j;
        const int l = l_of_m(m);
        const float* Wl = W + l * (F * F);
        float a = 0.0f;
#pragma unroll 8
        for (int f = 0; f < F; f++) a += aggL[m * F + f] * Wl[f * F + g];
        h[j] = a;
    }
    if (mb == 0) h0L[g] = h[0];
    __syncthreads();
    const float s = h0L[g];
    const float c0 = w_poly0[(0 * NSPEC + sp) * F + g];
    const float c1 = w_poly0[(1 * NSPEC + sp) * F + g];
    const float c2 = w_poly0[(2 * NSPEC + sp) * F + g];
    const float scale = c0 + c1 * s + c2 * s * s;
    float f0val = 0.0f;
#pragma unroll
    for (int j = 0; j < 4; j++) {
        const int m = mb * 4 + j;
        const float fv = h[j] * scale;
        feats_t[(size_t)n * (F * LDIM) + m * F + g] = fv;
        if (m == 0) f0val = fv;
    }
    if (mb == 0) {
        float v = f0val * w_read0[g];
#pragma unroll
        for (int off = 32; off > 0; off >>= 1) v += __shfl_down(v, off);
        if (g == 0) out[(size_t)n * 2 + 0] = v;
    }
}

__global__ void node1_kernel(const float* __restrict__ agg_t,
                             const float* __restrict__ feats_t,
                             const int* __restrict__ specie,
                             const float* __restrict__ w_skip1,
                             const float* __restrict__ w_poly1,
                             const float* __restrict__ w_mlp1,
                             const float* __restrict__ w_mlp2,
                             float* __restrict__ out, int N) {
    const int wave = threadIdx.x >> 6;
    const int lane = threadIdx.x & 63;
    const int n = blockIdx.x * 4 + wave;
    const int sp = specie[n];
    const float* W0 = w_skip1 + (size_t)sp * 4 * F * F;
    const float fv = feats_t[(size_t)n * (F * LDIM) + lane];
    float sc0 = 0.0f;
#pragma unroll 8
    for (int f = 0; f < F; f++) {
        const float ff = __shfl(fv, f);
        sc0 += ff * W0[f * F + lane];
    }
    const float h0 = agg_t[(size_t)n * (F * LDIM) + lane];
    const float c0 = w_poly1[(0 * NSPEC + sp) * F + lane];
    const float c1 = w_poly1[(1 * NSPEC + sp) * F + lane];
    const float c2 = w_poly1[(2 * NSPEC + sp) * F + lane];
    const float scale = c0 + c1 * h0 + c2 * h0 * h0;
    const float f2 = h0 * scale + sc0;
    float acc = 0.0f;
#pragma unroll 8
    for (int gg = 0; gg < F; gg++) {
        const float fg = __shfl(f2, gg);
        if (lane < HID_READ) acc += fg * w_mlp1[gg * HID_READ + lane];
    }
    float o = 0.0f;
    if (lane < HID_READ) o = silu(acc) * w_mlp2[lane];
#pragma unroll
    for (int off = 32; off > 0; off >>= 1) o += __shfl_down(o, off);
    if (lane == 0) out[(size_t)n * 2 + 1] = o;
}

// ---------- fallback (round-1, known-passing) edge kernel ----------
__global__ void edge_kernel(const float* __restrict__ Y, const float* __restrict__ Remb,
                            const float* __restrict__ feats_t,
                            const int* __restrict__ senders, const int* __restrict__ receivers,
                            const float* __restrict__ w1, const float* __restrict__ w2,
                            float* __restrict__ agg_t, int E) {
    const int wave = threadIdx.x >> 6;
    const int lane = threadIdx.x & 63;
    const int e = blockIdx.x * 4 + wave;
    __shared__ float hbuf[4][64];
    const float* remb = Remb + (size_t)e * NRAD;
    float acc = 0.0f;
#pragma unroll
    for (int k = 0; k < NRAD; k++) acc += remb[k] * w1[k * F + lane];
    hbuf[wave][lane] = silu(acc);
    __syncthreads();
    float r8[8] = {0.f, 0.f, 0.f, 0.f, 0.f, 0.f, 0.f, 0.f};
    const float* w2base = w2 + lane * 8;
#pragma unroll 8
    for (int j = 0; j < HID_R; j++) {
        float hj = hbuf[wave][j];
        const float4 a = *(const float4*)(w2base + j * 512);
        const float4 b = *(const float4*)(w2base + j * 512 + 4);
        r8[0] += hj * a.x; r8[1] += hj * a.y; r8[2] += hj * a.z; r8[3] += hj * a.w;
        r8[4] += hj * b.x; r8[5] += hj * b.y; r8[6] += hj * b.z; r8[7] += hj * b.w;
    }
    const int snd = senders[e];
    const int rcv = receivers[e];
    const float* fsrc = feats_t + (size_t)snd * (F * LDIM);
    float* adst = agg_t + (size_t)rcv * (F * LDIM);
    const float s0 = fsrc[lane];
    const float* Ye = Y + (size_t)e * 16;
#pragma unroll
    for (int m = 0; m < LDIM; m++) {
        const int l = l_of_m(m);
        const float ym = Ye[m];
        const float fsm = fsrc[m * F + lane];
        const float val = r8[l * 2 + 0] * s0 * ym + r8[l * 2 + 1] * fsm;
        atomicAdd(adst + m * F + lane, val * 0.25f);
    }
}

static inline size_t alignup(size_t x) { return (x + 255) & ~(size_t)255; }

extern "C" void kernel_launch(void* const* d_in, const int* in_sizes, int n_in,
                              void* d_out, int out_size, void* d_ws, size_t ws_size,
                              hipStream_t stream) {
    const float* vectors   = (const float*)d_in[0];
    const int*   specie    = (const int*)d_in[1];
    const int*   senders   = (const int*)d_in[2];
    const int*   receivers = (const int*)d_in[3];
    const float* w_embed   = (const float*)d_in[4];
    const float* w_r1      = (const float*)d_in[5];
    const float* w_r2      = (const float*)d_in[6];
    const float* w_skip    = (const float*)d_in[7];
    const float* w_poly    = (const float*)d_in[8];
    const float* w_read0   = (const float*)d_in[9];
    const float* w_mlp1    = (const float*)d_in[10];
    const float* w_mlp2    = (const float*)d_in[11];
    float* out = (float*)d_out;

    const int E = in_sizes[0] / 3;   // 160000
    const int N = in_sizes[1];       // 10000

    // ---- fast-path workspace layout ----
    char* base = (char*)d_ws;
    size_t off = 0;
    float* Y      = (float*)(base + off); off += alignup((size_t)E * 16 * sizeof(float));
    float* feats  = (float*)(base + off); off += alignup((size_t)N * F * LDIM * sizeof(float));
    float* agg    = (float*)(base + off); off += alignup((size_t)N * F * LDIM * sizeof(float));
    unsigned short* Hb = (unsigned short*)(base + off); off += alignup((size_t)E * 64 * sizeof(unsigned short));
    int* cnt      = (int*)(base + off);   off += alignup((size_t)N * sizeof(int));
    int* cur      = (int*)(base + off);   off += alignup((size_t)N * sizeof(int));
    int* offs     = (int*)(base + off);   off += alignup((size_t)(N + 1) * sizeof(int));
    int* eidx     = (int*)(base + off);   off += alignup((size_t)E * sizeof(int));
    int* snd_csr  = (int*)(base + off);   off += alignup((size_t)E * sizeof(int));
    unsigned short* w2f = (unsigned short*)(base + off); off += alignup((size_t)2 * 32768 * sizeof(unsigned short));
    float* R      = (float*)(base + off);
    const size_t fixed = off;

    // chunk size from remaining workspace: 512 fp32 per edge
    long long remain = (long long)ws_size - (long long)fixed;
    int chunkE = (int)(remain / (512 * sizeof(float)));
    if (chunkE > 32768) chunkE = 32768;      // keep R L3-resident
    chunkE &= ~31;                            // multiple of 32

    const size_t aggBytes = (size_t)N * F * LDIM * sizeof(float);

    if (chunkE >= 1024) {
        // =========== fast path: chunked MFMA R-GEMM + CSR gather ===========
        conv_w2_kernel<<<2, 256, 0, stream>>>(w_r2, w2f);
        hipMemsetAsync(cnt, 0, (size_t)N * sizeof(int), stream);
        hipMemsetAsync(cur, 0, (size_t)N * sizeof(int), stream);
        hist_kernel<<<(E + 255) / 256, 256, 0, stream>>>(receivers, cnt, E);
        scan_kernel<<<1, 256, 0, stream>>>(cnt, offs, N);
        scatter_kernel<<<(E + 255) / 256, 256, 0, stream>>>(receivers, senders, offs, cur,
                                                            eidx, snd_csr, E);
        init_feats_kernel<<<N, 256, 0, stream>>>(w_embed, specie, feats, N);

        for (int layer = 0; layer < 2; layer++) {
            geo_h_layer_kernel<<<(E + 255) / 256, 256, 0, stream>>>(
                vectors, w_r1 + (size_t)layer * NRAD * HID_R, Y, Hb, E, layer == 0 ? 1 : 0);
            hipMemsetAsync(agg, 0, aggBytes, stream);
            const unsigned short* w2fl = w2f + (size_t)layer * 32768;
            for (int t0 = 0; t0 < E; t0 += chunkE) {
                int t1 = (t0 + chunkE < E) ? t0 + chunkE : E;
                int ngrp = (t1 - t0 + 31) / 32;
                rgemm_chunk_kernel<<<ngrp, 256, 0, stream>>>(Hb, w2fl, eidx, R, t0, t1);
                gather_chunk_kernel<<<(N + 3) / 4, 256, 0, stream>>>(R, Y, feats, snd_csr,
                                                                     eidx, offs, agg, N, t0, t1);
            }
            if (layer == 0) {
                node0_kernel<<<N, 256, 0, stream>>>(agg, specie,
                                                    w_skip + (size_t)0 * NSPEC * 4 * F * F,
                                                    w_poly + (size_t)0 * 3 * NSPEC * F,
                                                    w_read0, feats, out, N);
            } else {
                node1_kernel<<<N / 4, 256, 0, stream>>>(agg, feats, specie,
                                                        w_skip + (size_t)1 * NSPEC * 4 * F * F,
                                                        w_poly + (size_t)1 * 3 * NSPEC * F,
                                                        w_mlp1, w_mlp2, out, N);
            }
        }
    } else {
        // =========== fallback: round-1 atomic path (ws proven >= 97.4 MB) ===========
        size_t fo = 0;
        float* Yf    = (float*)(base + fo); fo += alignup((size_t)E * 16 * sizeof(float));
        float* Remb  = (float*)(base + fo); fo += alignup((size_t)E * NRAD * sizeof(float));
        float* featsF= (float*)(base + fo); fo += alignup((size_t)N * F * LDIM * sizeof(float));
        float* aggF  = (float*)(base + fo);

        geo_kernel<<<(E + 255) / 256, 256, 0, stream>>>(vectors, Yf, Remb, E);
        init_feats_kernel<<<N, 256, 0, stream>>>(w_embed, specie, featsF, N);
        hipMemsetAsync(aggF, 0, aggBytes, stream);
        edge_kernel<<<E / 4, 256, 0, stream>>>(Yf, Remb, featsF, senders, receivers,
                                               w_r1, w_r2, aggF, E);
        node0_kernel<<<N, 256, 0, stream>>>(aggF, specie,
                                            w_skip + (size_t)0 * NSPEC * 4 * F * F,
                                            w_poly + (size_t)0 * 3 * NSPEC * F,
                                            w_read0, featsF, out, N);
        hipMemsetAsync(aggF, 0, aggBytes, stream);
        edge_kernel<<<E / 4, 256, 0, stream>>>(Yf, Remb, featsF, senders, receivers,
                                               w_r1 + NRAD * HID_R, w_r2 + HID_R * 512,
                                               aggF, E);
        node1_kernel<<<N / 4, 256, 0, stream>>>(aggF, featsF, specie,
                                                w_skip + (size_t)1 * NSPEC * 4 * F * F,
                                                w_poly + (size_t)1 * 3 * NSPEC * F,
                                                w_mlp1, w_mlp2, out, N);
    }
}

// Round 4
// 650.057 us; speedup vs baseline: 3.3532x; 1.3067x over previous
//
#include <hip/hip_runtime.h>
#include <math.h>

#define F 64
#define LDIM 16
#define NRAD 8
#define HID_R 64
#define HID_READ 32
#define NSPEC 10

typedef __attribute__((ext_vector_type(8))) short short8v;
typedef __attribute__((ext_vector_type(4))) float f32x4;

__device__ __forceinline__ int l_of_m(int m) {
    return (m == 0) ? 0 : (m < 4) ? 1 : (m < 9) ? 2 : 3;
}
__device__ __forceinline__ float silu(float x) { return x / (1.0f + __expf(-x)); }
__device__ __forceinline__ unsigned short bf16bits(float x) {
    unsigned int u = __float_as_uint(x);
    u += 0x7fffu + ((u >> 16) & 1u);   // RNE
    return (unsigned short)(u >> 16);
}

__device__ __forceinline__ void geo_core(const float* __restrict__ vectors, int e,
                                         float* Ye_out, float* remb_out) {
    float vx = vectors[e * 3 + 0];
    float vy = vectors[e * 3 + 1];
    float vz = vectors[e * 3 + 2];
    float r = sqrtf(vx * vx + vy * vy + vz * vz + 1e-12f);
    float x = vx / r, y = vy / r, z = vz / r;
    float r2 = x * x + y * y + z * z;
    Ye_out[0]  = 1.0f;  Ye_out[1] = x;  Ye_out[2] = y;  Ye_out[3] = z;
    Ye_out[4]  = x * y; Ye_out[5] = y * z; Ye_out[6] = 3.0f * z * z - r2; Ye_out[7] = x * z;
    Ye_out[8]  = x * x - y * y;
    Ye_out[9]  = y * (3.0f * x * x - y * y);
    Ye_out[10] = x * y * z;
    Ye_out[11] = y * (5.0f * z * z - r2);
    Ye_out[12] = z * (5.0f * z * z - 3.0f * r2);
    Ye_out[13] = x * (5.0f * z * z - r2);
    Ye_out[14] = z * (x * x - y * y);
    Ye_out[15] = x * (x * x - 3.0f * y * y);
    float u = r / 5.0f;
    float env = (u < 1.0f) ? (1.0f - u) * (1.0f - u) * (1.0f + 2.0f * u) : 0.0f;
    float inv = env / (u + 1e-6f);
    const float PI = 3.14159265358979323846f;
#pragma unroll
    for (int k = 1; k <= NRAD; k++) remb_out[k - 1] = sinf(PI * (float)k * u) * inv;
}

// ---------- fast path: Y (layer 0 only) + one layer's H (bf16) ----------
__global__ void geo_h_layer_kernel(const float* __restrict__ vectors,
                                   const float* __restrict__ w1,   // (8,64) this layer
                                   float* __restrict__ Y,
                                   unsigned short* __restrict__ Hb, // (E,64) bf16
                                   int E, int writeY) {
    int e = blockIdx.x * 256 + threadIdx.x;
    if (e >= E) return;
    float ye[16], remb[NRAD];
    geo_core(vectors, e, ye, remb);
    if (writeY) {
        float4* Yd = (float4*)(Y + (size_t)e * 16);
        Yd[0] = make_float4(ye[0], ye[1], ye[2], ye[3]);
        Yd[1] = make_float4(ye[4], ye[5], ye[6], ye[7]);
        Yd[2] = make_float4(ye[8], ye[9], ye[10], ye[11]);
        Yd[3] = make_float4(ye[12], ye[13], ye[14], ye[15]);
    }
    float h[HID_R];
#pragma unroll
    for (int j = 0; j < HID_R; j++) {
        float a = 0.0f;
#pragma unroll
        for (int k = 0; k < NRAD; k++) a += remb[k] * w1[k * HID_R + j];
        h[j] = silu(a);
    }
    unsigned int* dst = (unsigned int*)(Hb + (size_t)e * HID_R);
#pragma unroll
    for (int w = 0; w < 32; w++) {
        unsigned int lo = bf16bits(h[2 * w]);
        unsigned int hi = bf16bits(h[2 * w + 1]);
        dst[w] = lo | (hi << 16);
    }
}

// ---------- fallback geo ----------
__global__ void geo_kernel(const float* __restrict__ vectors,
                           float* __restrict__ Y, float* __restrict__ Remb, int E) {
    int e = blockIdx.x * 256 + threadIdx.x;
    if (e >= E) return;
    float ye[16], remb[NRAD];
    geo_core(vectors, e, ye, remb);
#pragma unroll
    for (int m = 0; m < 16; m++) Y[(size_t)e * 16 + m] = ye[m];
#pragma unroll
    for (int k = 0; k < NRAD; k++) Remb[(size_t)e * NRAD + k] = remb[k];
}

// ---------- w2 -> MFMA B-fragment layout, bf16 ----------
__global__ void conv_w2_kernel(const float* __restrict__ w_r2,
                               unsigned short* __restrict__ w2f) {
    int layer = blockIdx.x;
    const float* src = w_r2 + (size_t)layer * HID_R * 512;
    unsigned short* dst = w2f + (size_t)layer * 32768;
    for (int idx = threadIdx.x; idx < 32768; idx += 256) {
        int j    = idx & 7;
        int lane = (idx >> 3) & 63;
        int ks   = (idx >> 9) & 1;
        int ct   = idx >> 10;
        int k    = ks * 32 + (lane >> 4) * 8 + j;
        int col  = ct * 16 + (lane & 15);
        dst[idx] = bf16bits(src[k * 512 + col]);
    }
}

// ---------- CSR build ----------
__global__ void hist_kernel(const int* __restrict__ receivers, int* __restrict__ cnt, int E) {
    int e = blockIdx.x * 256 + threadIdx.x;
    if (e < E) atomicAdd(&cnt[receivers[e]], 1);
}

__global__ void scan_kernel(const int* __restrict__ cnt, int* __restrict__ offs, int N) {
    __shared__ int buf[256];
    __shared__ int carry;
    int t = threadIdx.x;
    if (t == 0) carry = 0;
    __syncthreads();
    for (int base = 0; base < N; base += 256) {
        int v = (base + t < N) ? cnt[base + t] : 0;
        buf[t] = v;
        __syncthreads();
#pragma unroll
        for (int off = 1; off < 256; off <<= 1) {
            int x = (t >= off) ? buf[t - off] : 0;
            __syncthreads();
            buf[t] += x;
            __syncthreads();
        }
        if (base + t < N) offs[base + t] = carry + buf[t] - v;   // exclusive
        __syncthreads();
        if (t == 0) carry += buf[255];
        __syncthreads();
    }
    if (t == 0) offs[N] = carry;
}

__global__ void scatter_kernel(const int* __restrict__ receivers,
                               const int* __restrict__ senders,
                               const int* __restrict__ offs, int* __restrict__ cur,
                               int* __restrict__ eidx, int* __restrict__ snd_csr,
                               int* __restrict__ rcv_csr, int E) {
    int e = blockIdx.x * 256 + threadIdx.x;
    if (e >= E) return;
    int r = receivers[e];
    int pos = atomicAdd(&cur[r], 1);
    int t = offs[r] + pos;
    eidx[t] = e;
    snd_csr[t] = senders[e];
    rcv_csr[t] = r;
}

// ---------- feats init (fallback only) ----------
__global__ void init_feats_kernel(const float* __restrict__ w_embed,
                                  const int* __restrict__ specie,
                                  float* __restrict__ feats_t, int N) {
    int n = blockIdx.x;
    int sp = specie[n];
    for (int i = threadIdx.x; i < F * LDIM; i += 256) {
        int m = i >> 6;
        int f = i & 63;
        feats_t[(size_t)n * (F * LDIM) + i] = (m == 0) ? w_embed[sp * F + f] : 0.0f;
    }
}

// ================= fused edge kernel: MFMA R (LDS) + weight + segment reduce =================
// block = 2 nodes (blockIdx.x*2, +1); edges = CSR [offs[n0], offs[n0+2]) in 32-edge batches.
// LDS R layout: addr = el*532 + lc*66 + f  (floats). Strides chosen so both the MFMA
// C-fragment writes and the per-(l,c) reads land 2 lanes/bank (conflict-free, m136).
template <bool L0>
__global__ __launch_bounds__(256, 2)
void fused_edge_kernel(const unsigned short* __restrict__ Hb,
                       const unsigned short* __restrict__ w2fl,  // this layer's frags
                       const float* __restrict__ Y,
                       const float* __restrict__ feats,
                       const float* __restrict__ w_embed,
                       const int* __restrict__ specie,
                       const int* __restrict__ offs,
                       const int* __restrict__ eidx,
                       const int* __restrict__ snd_csr,
                       const int* __restrict__ rcv_csr,
                       float* __restrict__ agg, int N) {
    __shared__ float R_lds[17024];   // 32 edges * 532 floats (swizzled)
    const int tid = threadIdx.x;
    const int wave = tid >> 6, lane = tid & 63;
    const int lo = lane & 15, hi = lane >> 4;
    const int g16 = wave & 1, chalf = wave >> 1;
    const int n0 = blockIdx.x * 2;
    const int segS = offs[n0], segE = offs[n0 + 2];
    const int mbase = wave * 4;

    int cur = -1;
    float acc[4] = {0.f, 0.f, 0.f, 0.f};

    for (int base = segS; base < segE; base += 32) {
        const int bend = (base + 32 < segE) ? base + 32 : segE;
        // ---------- phase 1: R for up to 32 CSR positions -> LDS ----------
        {
            int pos = base + g16 * 16 + lo;
            int cp = (pos < segE) ? pos : (segE - 1);
            int eid = eidx[cp];
            const unsigned short* hrow = Hb + (size_t)eid * 64;
            const short8v a0 = *(const short8v*)(hrow + hi * 8);
            const short8v a1 = *(const short8v*)(hrow + 32 + hi * 8);
            f32x4 c16[16];
#pragma unroll
            for (int i = 0; i < 16; i++) c16[i] = (f32x4)(0.f);
#pragma unroll
            for (int tt = 0; tt < 16; tt++) {
                const int ct = chalf * 16 + tt;
                const short8v b0 = *(const short8v*)(w2fl + ct * 1024 + lane * 8);
                const short8v b1 = *(const short8v*)(w2fl + ct * 1024 + 512 + lane * 8);
                c16[tt] = __builtin_amdgcn_mfma_f32_16x16x32_bf16(a0, b0, c16[tt], 0, 0, 0);
                c16[tt] = __builtin_amdgcn_mfma_f32_16x16x32_bf16(a1, b1, c16[tt], 0, 0, 0);
            }
            const int lc = lo & 7;
#pragma unroll
            for (int tt = 0; tt < 16; tt++) {
                const int ct = chalf * 16 + tt;
                const int f = ct * 2 + (lo >> 3);   // col>>3
#pragma unroll
                for (int r = 0; r < 4; r++) {
                    const int el = g16 * 16 + hi * 4 + r;
                    R_lds[el * 532 + lc * 66 + f] = c16[tt][r];
                }
            }
        }
        __syncthreads();
        // ---------- phase 2: weight + reduce (each wave: its 4 m's, lane = f) ----------
        for (int t = base; t < bend; t++) {
            const int node = rcv_csr[t];
            if (node != cur) {
                if (cur >= 0) {
#pragma unroll
                    for (int j = 0; j < 4; j++)
                        agg[(size_t)cur * 1024 + (mbase + j) * 64 + lane] = acc[j] * 0.25f;
                }
#pragma unroll
                for (int j = 0; j < 4; j++) acc[j] = 0.f;
                cur = node;
            }
            const int snd = snd_csr[t];
            const int eid = eidx[t];
            const float* ye = Y + (size_t)eid * 16;
            float s0;
            const float* fs = nullptr;
            if (L0) {
                s0 = w_embed[specie[snd] * 64 + lane];
            } else {
                fs = feats + (size_t)snd * 1024;
                s0 = fs[lane];
            }
            const float* Rt = R_lds + (t - base) * 532;
#pragma unroll
            for (int j = 0; j < 4; j++) {
                const int m = mbase + j;
                const int l = l_of_m(m);
                const float r0 = Rt[(2 * l) * 66 + lane];
                const float r1 = Rt[(2 * l + 1) * 66 + lane];
                const float fsm = L0 ? ((m == 0) ? s0 : 0.f) : fs[m * 64 + lane];
                acc[j] += r0 * s0 * ye[m] + r1 * fsm;
            }
        }
        __syncthreads();
    }
    if (cur >= 0) {
#pragma unroll
        for (int j = 0; j < 4; j++)
            agg[(size_t)cur * 1024 + (mbase + j) * 64 + lane] = acc[j] * 0.25f;
    }
    // zero-degree nodes: write zeros (agg is poisoned, never memset)
#pragma unroll
    for (int d = 0; d < 2; d++) {
        const int nn = n0 + d;
        if (nn < N && offs[nn] == offs[nn + 1]) {
#pragma unroll
            for (int j = 0; j < 4; j++)
                agg[(size_t)nn * 1024 + (mbase + j) * 64 + lane] = 0.f;
        }
    }
}

// ---------- node kernel, layer 0 (shfl-broadcast, W reused per l) ----------
__global__ void node0_kernel(const float* __restrict__ agg,
                             const int* __restrict__ specie,
                             const float* __restrict__ w_skip0,
                             const float* __restrict__ w_poly0,
                             const float* __restrict__ w_read0,
                             float* __restrict__ feats,
                             float* __restrict__ out, int N) {
    const int n = blockIdx.x;
    const int g = threadIdx.x & 63;
    const int mb = threadIdx.x >> 6;
    const int sp = specie[n];
    const float* W = w_skip0 + (size_t)sp * 4 * F * F;

    float areg[4];
#pragma unroll
    for (int j = 0; j < 4; j++) areg[j] = agg[(size_t)n * 1024 + (mb * 4 + j) * 64 + g];

    float h[4] = {0.f, 0.f, 0.f, 0.f};
    if (mb == 0) {            // m0 -> l0 ; m1..3 -> l1
        const float* W0 = W;
        const float* W1 = W + 4096;
#pragma unroll
        for (int f = 0; f < 64; f++) {
            const float w0 = W0[f * 64 + g];
            const float w1 = W1[f * 64 + g];
            h[0] += __shfl(areg[0], f) * w0;
            h[1] += __shfl(areg[1], f) * w1;
            h[2] += __shfl(areg[2], f) * w1;
            h[3] += __shfl(areg[3], f) * w1;
        }
    } else if (mb == 1) {     // m4..7 -> l2
        const float* W2 = W + 8192;
#pragma unroll
        for (int f = 0; f < 64; f++) {
            const float w2 = W2[f * 64 + g];
            h[0] += __shfl(areg[0], f) * w2;
            h[1] += __shfl(areg[1], f) * w2;
            h[2] += __shfl(areg[2], f) * w2;
            h[3] += __shfl(areg[3], f) * w2;
        }
    } else if (mb == 2) {     // m8 -> l2 ; m9..11 -> l3
        const float* W2 = W + 8192;
        const float* W3 = W + 12288;
#pragma unroll
        for (int f = 0; f < 64; f++) {
            const float w2 = W2[f * 64 + g];
            const float w3 = W3[f * 64 + g];
            h[0] += __shfl(areg[0], f) * w2;
            h[1] += __shfl(areg[1], f) * w3;
            h[2] += __shfl(areg[2], f) * w3;
            h[3] += __shfl(areg[3], f) * w3;
        }
    } else {                  // m12..15 -> l3
        const float* W3 = W + 12288;
#pragma unroll
        for (int f = 0; f < 64; f++) {
            const float w3 = W3[f * 64 + g];
            h[0] += __shfl(areg[0], f) * w3;
            h[1] += __shfl(areg[1], f) * w3;
            h[2] += __shfl(areg[2], f) * w3;
            h[3] += __shfl(areg[3], f) * w3;
        }
    }

    __shared__ float h0L[64];
    if (mb == 0) h0L[g] = h[0];
    __syncthreads();
    const float s = h0L[g];
    const float c0 = w_poly0[(0 * NSPEC + sp) * F + g];
    const float c1 = w_poly0[(1 * NSPEC + sp) * F + g];
    const float c2 = w_poly0[(2 * NSPEC + sp) * F + g];
    const float scale = c0 + c1 * s + c2 * s * s;
    float f0val = 0.0f;
#pragma unroll
    for (int j = 0; j < 4; j++) {
        const int m = mb * 4 + j;
        const float fv = h[j] * scale;
        feats[(size_t)n * 1024 + m * 64 + g] = fv;
        if (m == 0) f0val = fv;
    }
    if (mb == 0) {
        float v = f0val * w_read0[g];
#pragma unroll
        for (int off = 32; off > 0; off >>= 1) v += __shfl_down(v, off);
        if (g == 0) out[(size_t)n * 2 + 0] = v;
    }
}

// ---------- node kernel, layer 1 (verified) ----------
__global__ void node1_kernel(const float* __restrict__ agg,
                             const float* __restrict__ feats,
                             const int* __restrict__ specie,
                             const float* __restrict__ w_skip1,
                             const float* __restrict__ w_poly1,
                             const float* __restrict__ w_mlp1,
                             const float* __restrict__ w_mlp2,
                             float* __restrict__ out, int N) {
    const int wave = threadIdx.x >> 6;
    const int lane = threadIdx.x & 63;
    const int n = blockIdx.x * 4 + wave;
    const int sp = specie[n];
    const float* W0 = w_skip1 + (size_t)sp * 4 * F * F;
    const float fv = feats[(size_t)n * 1024 + lane];
    float sc0 = 0.0f;
#pragma unroll 8
    for (int f = 0; f < F; f++) {
        const float ff = __shfl(fv, f);
        sc0 += ff * W0[f * F + lane];
    }
    const float h0 = agg[(size_t)n * 1024 + lane];
    const float c0 = w_poly1[(0 * NSPEC + sp) * F + lane];
    const float c1 = w_poly1[(1 * NSPEC + sp) * F + lane];
    const float c2 = w_poly1[(2 * NSPEC + sp) * F + lane];
    const float scale = c0 + c1 * h0 + c2 * h0 * h0;
    const float f2 = h0 * scale + sc0;
    float acc = 0.0f;
#pragma unroll 8
    for (int gg = 0; gg < F; gg++) {
        const float fg = __shfl(f2, gg);
        if (lane < HID_READ) acc += fg * w_mlp1[gg * HID_READ + lane];
    }
    float o = 0.0f;
    if (lane < HID_READ) o = silu(acc) * w_mlp2[lane];
#pragma unroll
    for (int off = 32; off > 0; off >>= 1) o += __shfl_down(o, off);
    if (lane == 0) out[(size_t)n * 2 + 1] = o;
}

// ---------- fallback (round-1, known-passing) edge kernel ----------
__global__ void edge_kernel(const float* __restrict__ Y, const float* __restrict__ Remb,
                            const float* __restrict__ feats_t,
                            const int* __restrict__ senders, const int* __restrict__ receivers,
                            const float* __restrict__ w1, const float* __restrict__ w2,
                            float* __restrict__ agg_t, int E) {
    const int wave = threadIdx.x >> 6;
    const int lane = threadIdx.x & 63;
    const int e = blockIdx.x * 4 + wave;
    __shared__ float hbuf[4][64];
    const float* remb = Remb + (size_t)e * NRAD;
    float acc = 0.0f;
#pragma unroll
    for (int k = 0; k < NRAD; k++) acc += remb[k] * w1[k * F + lane];
    hbuf[wave][lane] = silu(acc);
    __syncthreads();
    float r8[8] = {0.f, 0.f, 0.f, 0.f, 0.f, 0.f, 0.f, 0.f};
    const float* w2base = w2 + lane * 8;
#pragma unroll 8
    for (int j = 0; j < HID_R; j++) {
        float hj = hbuf[wave][j];
        const float4 a = *(const float4*)(w2base + j * 512);
        const float4 b = *(const float4*)(w2base + j * 512 + 4);
        r8[0] += hj * a.x; r8[1] += hj * a.y; r8[2] += hj * a.z; r8[3] += hj * a.w;
        r8[4] += hj * b.x; r8[5] += hj * b.y; r8[6] += hj * b.z; r8[7] += hj * b.w;
    }
    const int snd = senders[e];
    const int rcv = receivers[e];
    const float* fsrc = feats_t + (size_t)snd * (F * LDIM);
    float* adst = agg_t + (size_t)rcv * (F * LDIM);
    const float s0 = fsrc[lane];
    const float* Ye = Y + (size_t)e * 16;
#pragma unroll
    for (int m = 0; m < LDIM; m++) {
        const int l = l_of_m(m);
        const float ym = Ye[m];
        const float fsm = fsrc[m * F + lane];
        const float val = r8[l * 2 + 0] * s0 * ym + r8[l * 2 + 1] * fsm;
        atomicAdd(adst + m * F + lane, val * 0.25f);
    }
}

static inline size_t alignup(size_t x) { return (x + 255) & ~(size_t)255; }

extern "C" void kernel_launch(void* const* d_in, const int* in_sizes, int n_in,
                              void* d_out, int out_size, void* d_ws, size_t ws_size,
                              hipStream_t stream) {
    const float* vectors   = (const float*)d_in[0];
    const int*   specie    = (const int*)d_in[1];
    const int*   senders   = (const int*)d_in[2];
    const int*   receivers = (const int*)d_in[3];
    const float* w_embed   = (const float*)d_in[4];
    const float* w_r1      = (const float*)d_in[5];
    const float* w_r2      = (const float*)d_in[6];
    const float* w_skip    = (const float*)d_in[7];
    const float* w_poly    = (const float*)d_in[8];
    const float* w_read0   = (const float*)d_in[9];
    const float* w_mlp1    = (const float*)d_in[10];
    const float* w_mlp2    = (const float*)d_in[11];
    float* out = (float*)d_out;

    const int E = in_sizes[0] / 3;   // 160000
    const int N = in_sizes[1];       // 10000

    // ---- fast-path workspace layout (~115 MB) ----
    char* base = (char*)d_ws;
    size_t off = 0;
    float* Y      = (float*)(base + off); off += alignup((size_t)E * 16 * sizeof(float));
    float* feats  = (float*)(base + off); off += alignup((size_t)N * F * LDIM * sizeof(float));
    float* agg    = (float*)(base + off); off += alignup((size_t)N * F * LDIM * sizeof(float));
    unsigned short* Hb = (unsigned short*)(base + off); off += alignup((size_t)E * 64 * sizeof(unsigned short));
    int* cnt      = (int*)(base + off);   off += alignup((size_t)N * sizeof(int));
    int* cur      = (int*)(base + off);   off += alignup((size_t)N * sizeof(int));
    int* offs     = (int*)(base + off);   off += alignup((size_t)(N + 1) * sizeof(int));
    int* eidx     = (int*)(base + off);   off += alignup((size_t)E * sizeof(int));
    int* snd_csr  = (int*)(base + off);   off += alignup((size_t)E * sizeof(int));
    int* rcv_csr  = (int*)(base + off);   off += alignup((size_t)E * sizeof(int));
    unsigned short* w2f = (unsigned short*)(base + off); off += alignup((size_t)2 * 32768 * sizeof(unsigned short));
    const size_t need = off;

    const size_t aggBytes = (size_t)N * F * LDIM * sizeof(float);

    if (ws_size >= need) {
        // =========== fast path: fused MFMA-in-LDS edge kernel, no atomics ===========
        conv_w2_kernel<<<2, 256, 0, stream>>>(w_r2, w2f);
        hipMemsetAsync(cnt, 0, (size_t)N * sizeof(int), stream);
        hipMemsetAsync(cur, 0, (size_t)N * sizeof(int), stream);
        hist_kernel<<<(E + 255) / 256, 256, 0, stream>>>(receivers, cnt, E);
        scan_kernel<<<1, 256, 0, stream>>>(cnt, offs, N);
        scatter_kernel<<<(E + 255) / 256, 256, 0, stream>>>(receivers, senders, offs, cur,
                                                            eidx, snd_csr, rcv_csr, E);
        // ---- layer 0 ----
        geo_h_layer_kernel<<<(E + 255) / 256, 256, 0, stream>>>(
            vectors, w_r1, Y, Hb, E, 1);
        fused_edge_kernel<true><<<N / 2, 256, 0, stream>>>(
            Hb, w2f, Y, nullptr, w_embed, specie, offs, eidx, snd_csr, rcv_csr, agg, N);
        node0_kernel<<<N, 256, 0, stream>>>(agg, specie,
                                            w_skip + (size_t)0 * NSPEC * 4 * F * F,
                                            w_poly + (size_t)0 * 3 * NSPEC * F,
                                            w_read0, feats, out, N);
        // ---- layer 1 ----
        geo_h_layer_kernel<<<(E + 255) / 256, 256, 0, stream>>>(
            vectors, w_r1 + NRAD * HID_R, Y, Hb, E, 0);
        fused_edge_kernel<false><<<N / 2, 256, 0, stream>>>(
            Hb, w2f + 32768, Y, feats, w_embed, specie, offs, eidx, snd_csr, rcv_csr, agg, N);
        node1_kernel<<<N / 4, 256, 0, stream>>>(agg, feats, specie,
                                                w_skip + (size_t)1 * NSPEC * 4 * F * F,
                                                w_poly + (size_t)1 * 3 * NSPEC * F,
                                                w_mlp1, w_mlp2, out, N);
    } else {
        // =========== fallback: round-1 atomic path ===========
        size_t fo = 0;
        float* Yf    = (float*)(base + fo); fo += alignup((size_t)E * 16 * sizeof(float));
        float* Remb  = (float*)(base + fo); fo += alignup((size_t)E * NRAD * sizeof(float));
        float* featsF= (float*)(base + fo); fo += alignup((size_t)N * F * LDIM * sizeof(float));
        float* aggF  = (float*)(base + fo);

        geo_kernel<<<(E + 255) / 256, 256, 0, stream>>>(vectors, Yf, Remb, E);
        init_feats_kernel<<<N, 256, 0, stream>>>(w_embed, specie, featsF, N);
        hipMemsetAsync(aggF, 0, aggBytes, stream);
        edge_kernel<<<E / 4, 256, 0, stream>>>(Yf, Remb, featsF, senders, receivers,
                                               w_r1, w_r2, aggF, E);
        node0_kernel<<<N, 256, 0, stream>>>(aggF, specie,
                                            w_skip + (size_t)0 * NSPEC * 4 * F * F,
                                            w_poly + (size_t)0 * 3 * NSPEC * F,
                                            w_read0, featsF, out, N);
        hipMemsetAsync(aggF, 0, aggBytes, stream);
        edge_kernel<<<E / 4, 256, 0, stream>>>(Yf, Remb, featsF, senders, receivers,
                                               w_r1 + NRAD * HID_R, w_r2 + HID_R * 512,
                                               aggF, E);
        node1_kernel<<<N / 4, 256, 0, stream>>>(aggF, featsF, specie,
                                                w_skip + (size_t)1 * NSPEC * 4 * F * F,
                                                w_poly + (size_t)1 * 3 * NSPEC * F,
                                                w_mlp1, w_mlp2, out, N);
    }
}

// Round 5
// 500.152 us; speedup vs baseline: 4.3583x; 1.2997x over previous
//
#include <hip/hip_runtime.h>
#include <math.h>

#define F 64
#define LDIM 16
#define NRAD 8
#define HID_R 64
#define HID_READ 32
#define NSPEC 10

typedef __attribute__((ext_vector_type(8))) short short8v;
typedef __attribute__((ext_vector_type(4))) float f32x4;

__device__ __forceinline__ int l_of_m(int m) {
    return (m == 0) ? 0 : (m < 4) ? 1 : (m < 9) ? 2 : 3;
}
__device__ __forceinline__ float silu(float x) { return x / (1.0f + __expf(-x)); }
__device__ __forceinline__ unsigned short bf16bits(float x) {
    unsigned int u = __float_as_uint(x);
    u += 0x7fffu + ((u >> 16) & 1u);   // RNE
    return (unsigned short)(u >> 16);
}

__device__ __forceinline__ void geo_core(const float* __restrict__ vectors, int e,
                                         float* Ye_out, float* remb_out) {
    float vx = vectors[e * 3 + 0];
    float vy = vectors[e * 3 + 1];
    float vz = vectors[e * 3 + 2];
    float r = sqrtf(vx * vx + vy * vy + vz * vz + 1e-12f);
    float x = vx / r, y = vy / r, z = vz / r;
    float r2 = x * x + y * y + z * z;
    Ye_out[0]  = 1.0f;  Ye_out[1] = x;  Ye_out[2] = y;  Ye_out[3] = z;
    Ye_out[4]  = x * y; Ye_out[5] = y * z; Ye_out[6] = 3.0f * z * z - r2; Ye_out[7] = x * z;
    Ye_out[8]  = x * x - y * y;
    Ye_out[9]  = y * (3.0f * x * x - y * y);
    Ye_out[10] = x * y * z;
    Ye_out[11] = y * (5.0f * z * z - r2);
    Ye_out[12] = z * (5.0f * z * z - 3.0f * r2);
    Ye_out[13] = x * (5.0f * z * z - r2);
    Ye_out[14] = z * (x * x - y * y);
    Ye_out[15] = x * (x * x - 3.0f * y * y);
    float u = r / 5.0f;
    float env = (u < 1.0f) ? (1.0f - u) * (1.0f - u) * (1.0f + 2.0f * u) : 0.0f;
    float inv = env / (u + 1e-6f);
    const float PI = 3.14159265358979323846f;
#pragma unroll
    for (int k = 1; k <= NRAD; k++) remb_out[k - 1] = sinf(PI * (float)k * u) * inv;
}

// ---------- fast path: Y (layer 0 only) + one layer's H (bf16) ----------
__global__ void geo_h_layer_kernel(const float* __restrict__ vectors,
                                   const float* __restrict__ w1,   // (8,64) this layer
                                   float* __restrict__ Y,
                                   unsigned short* __restrict__ Hb, // (E,64) bf16
                                   int E, int writeY) {
    int e = blockIdx.x * 256 + threadIdx.x;
    if (e >= E) return;
    float ye[16], remb[NRAD];
    geo_core(vectors, e, ye, remb);
    if (writeY) {
        float4* Yd = (float4*)(Y + (size_t)e * 16);
        Yd[0] = make_float4(ye[0], ye[1], ye[2], ye[3]);
        Yd[1] = make_float4(ye[4], ye[5], ye[6], ye[7]);
        Yd[2] = make_float4(ye[8], ye[9], ye[10], ye[11]);
        Yd[3] = make_float4(ye[12], ye[13], ye[14], ye[15]);
    }
    float h[HID_R];
#pragma unroll
    for (int j = 0; j < HID_R; j++) {
        float a = 0.0f;
#pragma unroll
        for (int k = 0; k < NRAD; k++) a += remb[k] * w1[k * HID_R + j];
        h[j] = silu(a);
    }
    unsigned int* dst = (unsigned int*)(Hb + (size_t)e * HID_R);
#pragma unroll
    for (int w = 0; w < 32; w++) {
        unsigned int lo = bf16bits(h[2 * w]);
        unsigned int hi = bf16bits(h[2 * w + 1]);
        dst[w] = lo | (hi << 16);
    }
}

// ---------- fallback geo ----------
__global__ void geo_kernel(const float* __restrict__ vectors,
                           float* __restrict__ Y, float* __restrict__ Remb, int E) {
    int e = blockIdx.x * 256 + threadIdx.x;
    if (e >= E) return;
    float ye[16], remb[NRAD];
    geo_core(vectors, e, ye, remb);
#pragma unroll
    for (int m = 0; m < 16; m++) Y[(size_t)e * 16 + m] = ye[m];
#pragma unroll
    for (int k = 0; k < NRAD; k++) Remb[(size_t)e * NRAD + k] = remb[k];
}

// ---------- w2 -> MFMA B-fragment layout, bf16 ----------
__global__ void conv_w2_kernel(const float* __restrict__ w_r2,
                               unsigned short* __restrict__ w2f) {
    int layer = blockIdx.x;
    const float* src = w_r2 + (size_t)layer * HID_R * 512;
    unsigned short* dst = w2f + (size_t)layer * 32768;
    for (int idx = threadIdx.x; idx < 32768; idx += 256) {
        int j    = idx & 7;
        int lane = (idx >> 3) & 63;
        int ks   = (idx >> 9) & 1;
        int ct   = idx >> 10;
        int k    = ks * 32 + (lane >> 4) * 8 + j;
        int col  = ct * 16 + (lane & 15);
        dst[idx] = bf16bits(src[k * 512 + col]);
    }
}

// ---------- CSR build ----------
__global__ void hist_kernel(const int* __restrict__ receivers, int* __restrict__ cnt, int E) {
    int e = blockIdx.x * 256 + threadIdx.x;
    if (e < E) atomicAdd(&cnt[receivers[e]], 1);
}

__global__ void scan_kernel(const int* __restrict__ cnt, int* __restrict__ offs, int N) {
    __shared__ int buf[256];
    __shared__ int carry;
    int t = threadIdx.x;
    if (t == 0) carry = 0;
    __syncthreads();
    for (int base = 0; base < N; base += 256) {
        int v = (base + t < N) ? cnt[base + t] : 0;
        buf[t] = v;
        __syncthreads();
#pragma unroll
        for (int off = 1; off < 256; off <<= 1) {
            int x = (t >= off) ? buf[t - off] : 0;
            __syncthreads();
            buf[t] += x;
            __syncthreads();
        }
        if (base + t < N) offs[base + t] = carry + buf[t] - v;   // exclusive
        __syncthreads();
        if (t == 0) carry += buf[255];
        __syncthreads();
    }
    if (t == 0) offs[N] = carry;
}

__global__ void scatter_kernel(const int* __restrict__ receivers,
                               const int* __restrict__ senders,
                               const int* __restrict__ offs, int* __restrict__ cur,
                               int* __restrict__ eidx, int* __restrict__ snd_csr,
                               int* __restrict__ rcv_csr, int E) {
    int e = blockIdx.x * 256 + threadIdx.x;
    if (e >= E) return;
    int r = receivers[e];
    int pos = atomicAdd(&cur[r], 1);
    int t = offs[r] + pos;
    eidx[t] = e;
    snd_csr[t] = senders[e];
    rcv_csr[t] = r;
}

// ---------- feats init (fallback only) ----------
__global__ void init_feats_kernel(const float* __restrict__ w_embed,
                                  const int* __restrict__ specie,
                                  float* __restrict__ feats_t, int N) {
    int n = blockIdx.x;
    int sp = specie[n];
    for (int i = threadIdx.x; i < F * LDIM; i += 256) {
        int m = i >> 6;
        int f = i & 63;
        feats_t[(size_t)n * (F * LDIM) + i] = (m == 0) ? w_embed[sp * F + f] : 0.0f;
    }
}

// ================= fused edge kernel: MFMA R (LDS) + weight + segment reduce =================
// block = 2 nodes; edges processed in 16-edge batches.
// LDS R layout: addr = el*532 + lc*66 + f (floats) -> both MFMA-frag writes and per-(l,c)
// reads hit <=2 lanes/bank (free, m136).  16*532*4 = 34,048 B -> 4 blocks/CU (50% occ).
template <bool L0>
__global__ __launch_bounds__(256, 4)
void fused_edge_kernel(const unsigned short* __restrict__ Hb,
                       const unsigned short* __restrict__ w2fl,  // this layer's frags
                       const float* __restrict__ Y,
                       const float* __restrict__ feats,
                       const float* __restrict__ w_embed,
                       const int* __restrict__ specie,
                       const int* __restrict__ offs,
                       const int* __restrict__ eidx,
                       const int* __restrict__ snd_csr,
                       const int* __restrict__ rcv_csr,
                       float* __restrict__ agg, int N) {
    __shared__ float R_lds[16 * 532];   // 34,048 B
    __shared__ float ysL[16][16];       // Y rows for the batch
    __shared__ int   ssL[16];           // senders
    __shared__ int   rsL[16];           // receivers
    const int tid = threadIdx.x;
    const int wave = tid >> 6, lane = tid & 63;
    const int lo = lane & 15, hi = lane >> 4;
    const int n0 = blockIdx.x * 2;
    const int segS = offs[n0], segE = offs[n0 + 2];
    const int mbase = wave * 4;

    int cur = -1;
    float acc[4] = {0.f, 0.f, 0.f, 0.f};

    for (int base = segS; base < segE; base += 16) {
        const int bend = (base + 16 < segE) ? base + 16 : segE;
        // ---------- phase 0: preload Y rows + edge metadata ----------
        {
            const int t = tid >> 4, m = tid & 15;
            const int pos = base + t;
            const int cp = (pos < segE) ? pos : (segE - 1);
            ysL[t][m] = Y[(size_t)eidx[cp] * 16 + m];
            if (tid < 16) {
                const int p2 = base + tid;
                const int c2 = (p2 < segE) ? p2 : (segE - 1);
                ssL[tid] = snd_csr[c2];
                rsL[tid] = rcv_csr[c2];
            }
        }
        // ---------- phase 1: MFMA 16 edges x 512 cols; wave -> 8 ct tiles ----------
        {
            const int pos = base + lo;
            const int cp = (pos < segE) ? pos : (segE - 1);
            const int eid = eidx[cp];
            const unsigned short* hrow = Hb + (size_t)eid * 64;
            const short8v a0 = *(const short8v*)(hrow + hi * 8);
            const short8v a1 = *(const short8v*)(hrow + 32 + hi * 8);
            f32x4 c16[8];
#pragma unroll
            for (int i = 0; i < 8; i++) c16[i] = (f32x4)(0.f);
#pragma unroll
            for (int tt = 0; tt < 8; tt++) {
                const int ct = wave * 8 + tt;
                const short8v b0 = *(const short8v*)(w2fl + ct * 1024 + lane * 8);
                const short8v b1 = *(const short8v*)(w2fl + ct * 1024 + 512 + lane * 8);
                c16[tt] = __builtin_amdgcn_mfma_f32_16x16x32_bf16(a0, b0, c16[tt], 0, 0, 0);
                c16[tt] = __builtin_amdgcn_mfma_f32_16x16x32_bf16(a1, b1, c16[tt], 0, 0, 0);
            }
            const int lc = lo & 7;
#pragma unroll
            for (int tt = 0; tt < 8; tt++) {
                const int ct = wave * 8 + tt;
                const int f = ct * 2 + (lo >> 3);   // col>>3
#pragma unroll
                for (int r = 0; r < 4; r++) {
                    const int el = hi * 4 + r;
                    R_lds[el * 532 + lc * 66 + f] = c16[tt][r];
                }
            }
        }
        __syncthreads();
        // ---------- phase 2: weight + segment reduce (wave: its 4 m's; lane = f) ----------
        for (int t = base; t < bend; t++) {
            const int node = rsL[t - base];
            if (node != cur) {
                if (cur >= 0) {
#pragma unroll
                    for (int j = 0; j < 4; j++)
                        agg[(size_t)cur * 1024 + (mbase + j) * 64 + lane] = acc[j] * 0.25f;
                }
#pragma unroll
                for (int j = 0; j < 4; j++) acc[j] = 0.f;
                cur = node;
            }
            const int snd = ssL[t - base];
            const float* ye = ysL[t - base];
            float s0;
            const float* fs = nullptr;
            if (L0) {
                s0 = w_embed[specie[snd] * 64 + lane];
            } else {
                fs = feats + (size_t)snd * 1024;
                s0 = fs[lane];
            }
            const float* Rt = R_lds + (t - base) * 532;
#pragma unroll
            for (int j = 0; j < 4; j++) {
                const int m = mbase + j;
                const int l = l_of_m(m);
                const float r0 = Rt[(2 * l) * 66 + lane];
                const float r1 = Rt[(2 * l + 1) * 66 + lane];
                const float fsm = L0 ? ((m == 0) ? s0 : 0.f) : fs[m * 64 + lane];
                acc[j] += r0 * s0 * ye[m] + r1 * fsm;
            }
        }
        __syncthreads();
    }
    if (cur >= 0) {
#pragma unroll
        for (int j = 0; j < 4; j++)
            agg[(size_t)cur * 1024 + (mbase + j) * 64 + lane] = acc[j] * 0.25f;
    }
    // zero-degree nodes: write zeros (agg is poisoned, never memset)
#pragma unroll
    for (int d = 0; d < 2; d++) {
        const int nn = n0 + d;
        if (nn < N && offs[nn] == offs[nn + 1]) {
#pragma unroll
            for (int j = 0; j < 4; j++)
                agg[(size_t)nn * 1024 + (mbase + j) * 64 + lane] = 0.f;
        }
    }
}

// ---------- node kernel, layer 0 (shfl-broadcast, W reused per l) ----------
__global__ void node0_kernel(const float* __restrict__ agg,
                             const int* __restrict__ specie,
                             const float* __restrict__ w_skip0,
                             const float* __restrict__ w_poly0,
                             const float* __restrict__ w_read0,
                             float* __restrict__ feats,
                             float* __restrict__ out, int N) {
    const int n = blockIdx.x;
    const int g = threadIdx.x & 63;
    const int mb = threadIdx.x >> 6;
    const int sp = specie[n];
    const float* W = w_skip0 + (size_t)sp * 4 * F * F;

    float areg[4];
#pragma unroll
    for (int j = 0; j < 4; j++) areg[j] = agg[(size_t)n * 1024 + (mb * 4 + j) * 64 + g];

    float h[4] = {0.f, 0.f, 0.f, 0.f};
    if (mb == 0) {            // m0 -> l0 ; m1..3 -> l1
        const float* W0 = W;
        const float* W1 = W + 4096;
#pragma unroll
        for (int f = 0; f < 64; f++) {
            const float w0 = W0[f * 64 + g];
            const float w1 = W1[f * 64 + g];
            h[0] += __shfl(areg[0], f) * w0;
            h[1] += __shfl(areg[1], f) * w1;
            h[2] += __shfl(areg[2], f) * w1;
            h[3] += __shfl(areg[3], f) * w1;
        }
    } else if (mb == 1) {     // m4..7 -> l2
        const float* W2 = W + 8192;
#pragma unroll
        for (int f = 0; f < 64; f++) {
            const float w2 = W2[f * 64 + g];
            h[0] += __shfl(areg[0], f) * w2;
            h[1] += __shfl(areg[1], f) * w2;
            h[2] += __shfl(areg[2], f) * w2;
            h[3] += __shfl(areg[3], f) * w2;
        }
    } else if (mb == 2) {     // m8 -> l2 ; m9..11 -> l3
        const float* W2 = W + 8192;
        const float* W3 = W + 12288;
#pragma unroll
        for (int f = 0; f < 64; f++) {
            const float w2 = W2[f * 64 + g];
            const float w3 = W3[f * 64 + g];
            h[0] += __shfl(areg[0], f) * w2;
            h[1] += __shfl(areg[1], f) * w3;
            h[2] += __shfl(areg[2], f) * w3;
            h[3] += __shfl(areg[3], f) * w3;
        }
    } else {                  // m12..15 -> l3
        const float* W3 = W + 12288;
#pragma unroll
        for (int f = 0; f < 64; f++) {
            const float w3 = W3[f * 64 + g];
            h[0] += __shfl(areg[0], f) * w3;
            h[1] += __shfl(areg[1], f) * w3;
            h[2] += __shfl(areg[2], f) * w3;
            h[3] += __shfl(areg[3], f) * w3;
        }
    }

    __shared__ float h0L[64];
    if (mb == 0) h0L[g] = h[0];
    __syncthreads();
    const float s = h0L[g];
    const float c0 = w_poly0[(0 * NSPEC + sp) * F + g];
    const float c1 = w_poly0[(1 * NSPEC + sp) * F + g];
    const float c2 = w_poly0[(2 * NSPEC + sp) * F + g];
    const float scale = c0 + c1 * s + c2 * s * s;
    float f0val = 0.0f;
#pragma unroll
    for (int j = 0; j < 4; j++) {
        const int m = mb * 4 + j;
        const float fv = h[j] * scale;
        feats[(size_t)n * 1024 + m * 64 + g] = fv;
        if (m == 0) f0val = fv;
    }
    if (mb == 0) {
        float v = f0val * w_read0[g];
#pragma unroll
        for (int off = 32; off > 0; off >>= 1) v += __shfl_down(v, off);
        if (g == 0) out[(size_t)n * 2 + 0] = v;
    }
}

// ---------- node kernel, layer 1 (verified) ----------
__global__ void node1_kernel(const float* __restrict__ agg,
                             const float* __restrict__ feats,
                             const int* __restrict__ specie,
                             const float* __restrict__ w_skip1,
                             const float* __restrict__ w_poly1,
                             const float* __restrict__ w_mlp1,
                             const float* __restrict__ w_mlp2,
                             float* __restrict__ out, int N) {
    const int wave = threadIdx.x >> 6;
    const int lane = threadIdx.x & 63;
    const int n = blockIdx.x * 4 + wave;
    const int sp = specie[n];
    const float* W0 = w_skip1 + (size_t)sp * 4 * F * F;
    const float fv = feats[(size_t)n * 1024 + lane];
    float sc0 = 0.0f;
#pragma unroll 8
    for (int f = 0; f < F; f++) {
        const float ff = __shfl(fv, f);
        sc0 += ff * W0[f * F + lane];
    }
    const float h0 = agg[(size_t)n * 1024 + lane];
    const float c0 = w_poly1[(0 * NSPEC + sp) * F + lane];
    const float c1 = w_poly1[(1 * NSPEC + sp) * F + lane];
    const float c2 = w_poly1[(2 * NSPEC + sp) * F + lane];
    const float scale = c0 + c1 * h0 + c2 * h0 * h0;
    const float f2 = h0 * scale + sc0;
    float acc = 0.0f;
#pragma unroll 8
    for (int gg = 0; gg < F; gg++) {
        const float fg = __shfl(f2, gg);
        if (lane < HID_READ) acc += fg * w_mlp1[gg * HID_READ + lane];
    }
    float o = 0.0f;
    if (lane < HID_READ) o = silu(acc) * w_mlp2[lane];
#pragma unroll
    for (int off = 32; off > 0; off >>= 1) o += __shfl_down(o, off);
    if (lane == 0) out[(size_t)n * 2 + 1] = o;
}

// ---------- fallback (round-1, known-passing) edge kernel ----------
__global__ void edge_kernel(const float* __restrict__ Y, const float* __restrict__ Remb,
                            const float* __restrict__ feats_t,
                            const int* __restrict__ senders, const int* __restrict__ receivers,
                            const float* __restrict__ w1, const float* __restrict__ w2,
                            float* __restrict__ agg_t, int E) {
    const int wave = threadIdx.x >> 6;
    const int lane = threadIdx.x & 63;
    const int e = blockIdx.x * 4 + wave;
    __shared__ float hbuf[4][64];
    const float* remb = Remb + (size_t)e * NRAD;
    float acc = 0.0f;
#pragma unroll
    for (int k = 0; k < NRAD; k++) acc += remb[k] * w1[k * F + lane];
    hbuf[wave][lane] = silu(acc);
    __syncthreads();
    float r8[8] = {0.f, 0.f, 0.f, 0.f, 0.f, 0.f, 0.f, 0.f};
    const float* w2base = w2 + lane * 8;
#pragma unroll 8
    for (int j = 0; j < HID_R; j++) {
        float hj = hbuf[wave][j];
        const float4 a = *(const float4*)(w2base + j * 512);
        const float4 b = *(const float4*)(w2base + j * 512 + 4);
        r8[0] += hj * a.x; r8[1] += hj * a.y; r8[2] += hj * a.z; r8[3] += hj * a.w;
        r8[4] += hj * b.x; r8[5] += hj * b.y; r8[6] += hj * b.z; r8[7] += hj * b.w;
    }
    const int snd = senders[e];
    const int rcv = receivers[e];
    const float* fsrc = feats_t + (size_t)snd * (F * LDIM);
    float* adst = agg_t + (size_t)rcv * (F * LDIM);
    const float s0 = fsrc[lane];
    const float* Ye = Y + (size_t)e * 16;
#pragma unroll
    for (int m = 0; m < LDIM; m++) {
        const int l = l_of_m(m);
        const float ym = Ye[m];
        const float fsm = fsrc[m * F + lane];
        const float val = r8[l * 2 + 0] * s0 * ym + r8[l * 2 + 1] * fsm;
        atomicAdd(adst + m * F + lane, val * 0.25f);
    }
}

static inline size_t alignup(size_t x) { return (x + 255) & ~(size_t)255; }

extern "C" void kernel_launch(void* const* d_in, const int* in_sizes, int n_in,
                              void* d_out, int out_size, void* d_ws, size_t ws_size,
                              hipStream_t stream) {
    const float* vectors   = (const float*)d_in[0];
    const int*   specie    = (const int*)d_in[1];
    const int*   senders   = (const int*)d_in[2];
    const int*   receivers = (const int*)d_in[3];
    const float* w_embed   = (const float*)d_in[4];
    const float* w_r1      = (const float*)d_in[5];
    const float* w_r2      = (const float*)d_in[6];
    const float* w_skip    = (const float*)d_in[7];
    const float* w_poly    = (const float*)d_in[8];
    const float* w_read0   = (const float*)d_in[9];
    const float* w_mlp1    = (const float*)d_in[10];
    const float* w_mlp2    = (const float*)d_in[11];
    float* out = (float*)d_out;

    const int E = in_sizes[0] / 3;   // 160000
    const int N = in_sizes[1];       // 10000

    // ---- fast-path workspace layout (~115 MB) ----
    char* base = (char*)d_ws;
    size_t off = 0;
    float* Y      = (float*)(base + off); off += alignup((size_t)E * 16 * sizeof(float));
    float* feats  = (float*)(base + off); off += alignup((size_t)N * F * LDIM * sizeof(float));
    float* agg    = (float*)(base + off); off += alignup((size_t)N * F * LDIM * sizeof(float));
    unsigned short* Hb = (unsigned short*)(base + off); off += alignup((size_t)E * 64 * sizeof(unsigned short));
    int* cnt      = (int*)(base + off);   off += alignup((size_t)N * sizeof(int));
    int* cur      = (int*)(base + off);   off += alignup((size_t)N * sizeof(int));
    int* offs     = (int*)(base + off);   off += alignup((size_t)(N + 1) * sizeof(int));
    int* eidx     = (int*)(base + off);   off += alignup((size_t)E * sizeof(int));
    int* snd_csr  = (int*)(base + off);   off += alignup((size_t)E * sizeof(int));
    int* rcv_csr  = (int*)(base + off);   off += alignup((size_t)E * sizeof(int));
    unsigned short* w2f = (unsigned short*)(base + off); off += alignup((size_t)2 * 32768 * sizeof(unsigned short));
    const size_t need = off;

    const size_t aggBytes = (size_t)N * F * LDIM * sizeof(float);

    if (ws_size >= need) {
        // =========== fast path: fused MFMA-in-LDS edge kernel, no atomics ===========
        conv_w2_kernel<<<2, 256, 0, stream>>>(w_r2, w2f);
        hipMemsetAsync(cnt, 0, (size_t)N * sizeof(int), stream);
        hipMemsetAsync(cur, 0, (size_t)N * sizeof(int), stream);
        hist_kernel<<<(E + 255) / 256, 256, 0, stream>>>(receivers, cnt, E);
        scan_kernel<<<1, 256, 0, stream>>>(cnt, offs, N);
        scatter_kernel<<<(E + 255) / 256, 256, 0, stream>>>(receivers, senders, offs, cur,
                                                            eidx, snd_csr, rcv_csr, E);
        // ---- layer 0 ----
        geo_h_layer_kernel<<<(E + 255) / 256, 256, 0, stream>>>(
            vectors, w_r1, Y, Hb, E, 1);
        fused_edge_kernel<true><<<N / 2, 256, 0, stream>>>(
            Hb, w2f, Y, nullptr, w_embed, specie, offs, eidx, snd_csr, rcv_csr, agg, N);
        node0_kernel<<<N, 256, 0, stream>>>(agg, specie,
                                            w_skip + (size_t)0 * NSPEC * 4 * F * F,
                                            w_poly + (size_t)0 * 3 * NSPEC * F,
                                            w_read0, feats, out, N);
        // ---- layer 1 ----
        geo_h_layer_kernel<<<(E + 255) / 256, 256, 0, stream>>>(
            vectors, w_r1 + NRAD * HID_R, Y, Hb, E, 0);
        fused_edge_kernel<false><<<N / 2, 256, 0, stream>>>(
            Hb, w2f + 32768, Y, feats, w_embed, specie, offs, eidx, snd_csr, rcv_csr, agg, N);
        node1_kernel<<<N / 4, 256, 0, stream>>>(agg, feats, specie,
                                                w_skip + (size_t)1 * NSPEC * 4 * F * F,
                                                w_poly + (size_t)1 * 3 * NSPEC * F,
                                                w_mlp1, w_mlp2, out, N);
    } else {
        // =========== fallback: round-1 atomic path ===========
        size_t fo = 0;
        float* Yf    = (float*)(base + fo); fo += alignup((size_t)E * 16 * sizeof(float));
        float* Remb  = (float*)(base + fo); fo += alignup((size_t)E * NRAD * sizeof(float));
        float* featsF= (float*)(base + fo); fo += alignup((size_t)N * F * LDIM * sizeof(float));
        float* aggF  = (float*)(base + fo);

        geo_kernel<<<(E + 255) / 256, 256, 0, stream>>>(vectors, Yf, Remb, E);
        init_feats_kernel<<<N, 256, 0, stream>>>(w_embed, specie, featsF, N);
        hipMemsetAsync(aggF, 0, aggBytes, stream);
        edge_kernel<<<E / 4, 256, 0, stream>>>(Yf, Remb, featsF, senders, receivers,
                                               w_r1, w_r2, aggF, E);
        node0_kernel<<<N, 256, 0, stream>>>(aggF, specie,
                                            w_skip + (size_t)0 * NSPEC * 4 * F * F,
                                            w_poly + (size_t)0 * 3 * NSPEC * F,
                                            w_read0, featsF, out, N);
        hipMemsetAsync(aggF, 0, aggBytes, stream);
        edge_kernel<<<E / 4, 256, 0, stream>>>(Yf, Remb, featsF, senders, receivers,
                                               w_r1 + NRAD * HID_R, w_r2 + HID_R * 512,
                                               aggF, E);
        node1_kernel<<<N / 4, 256, 0, stream>>>(aggF, featsF, specie,
                                                w_skip + (size_t)1 * NSPEC * 4 * F * F,
                                                w_poly + (size_t)1 * 3 * NSPEC * F,
                                                w_mlp1, w_mlp2, out, N);
    }
}

// Round 8
// 456.832 us; speedup vs baseline: 4.7715x; 1.0948x over previous
//
#include <hip/hip_runtime.h>
#include <math.h>

#define F 64
#define LDIM 16
#define NRAD 8
#define HID_R 64
#define HID_READ 32
#define NSPEC 10

typedef __attribute__((ext_vector_type(8))) short short8v;
typedef __attribute__((ext_vector_type(4))) float f32x4;

__device__ __forceinline__ int l_of_m(int m) {
    return (m == 0) ? 0 : (m < 4) ? 1 : (m < 9) ? 2 : 3;
}
__device__ __forceinline__ float silu(float x) { return x / (1.0f + __expf(-x)); }
__device__ __forceinline__ unsigned short bf16bits(float x) {
    unsigned int u = __float_as_uint(x);
    u += 0x7fffu + ((u >> 16) & 1u);   // RNE
    return (unsigned short)(u >> 16);
}

__device__ __forceinline__ void geo_core(const float* __restrict__ vectors, int e,
                                         float* Ye_out, float* remb_out) {
    float vx = vectors[e * 3 + 0];
    float vy = vectors[e * 3 + 1];
    float vz = vectors[e * 3 + 2];
    float r = sqrtf(vx * vx + vy * vy + vz * vz + 1e-12f);
    float x = vx / r, y = vy / r, z = vz / r;
    float r2 = x * x + y * y + z * z;
    Ye_out[0]  = 1.0f;  Ye_out[1] = x;  Ye_out[2] = y;  Ye_out[3] = z;
    Ye_out[4]  = x * y; Ye_out[5] = y * z; Ye_out[6] = 3.0f * z * z - r2; Ye_out[7] = x * z;
    Ye_out[8]  = x * x - y * y;
    Ye_out[9]  = y * (3.0f * x * x - y * y);
    Ye_out[10] = x * y * z;
    Ye_out[11] = y * (5.0f * z * z - r2);
    Ye_out[12] = z * (5.0f * z * z - 3.0f * r2);
    Ye_out[13] = x * (5.0f * z * z - r2);
    Ye_out[14] = z * (x * x - y * y);
    Ye_out[15] = x * (x * x - 3.0f * y * y);
    float u = r / 5.0f;
    float env = (u < 1.0f) ? (1.0f - u) * (1.0f - u) * (1.0f + 2.0f * u) : 0.0f;
    float inv = env / (u + 1e-6f);
    const float PI = 3.14159265358979323846f;
#pragma unroll
    for (int k = 1; k <= NRAD; k++) remb_out[k - 1] = sinf(PI * (float)k * u) * inv;
}

__device__ __forceinline__ void hid_write(const float* remb, const float* w1,
                                          unsigned short* __restrict__ Hb, int e) {
    float h[HID_R];
#pragma unroll
    for (int j = 0; j < HID_R; j++) {
        float a = 0.0f;
#pragma unroll
        for (int k = 0; k < NRAD; k++) a += remb[k] * w1[k * HID_R + j];
        h[j] = silu(a);
    }
    unsigned int* dst = (unsigned int*)(Hb + (size_t)e * HID_R);
#pragma unroll
    for (int w = 0; w < 32; w++) {
        unsigned int lo = bf16bits(h[2 * w]);
        unsigned int hi = bf16bits(h[2 * w + 1]);
        dst[w] = lo | (hi << 16);
    }
}

// =========== K1: geo+H(L0)+hist  |  conv_w2 (2 tail blocks) ===========
__global__ void k1_kernel(const float* __restrict__ vectors,
                          const float* __restrict__ w_r1,   // (2,8,64)
                          const float* __restrict__ w_r2,   // (2,64,512)
                          const int* __restrict__ receivers,
                          float* __restrict__ Y,
                          unsigned short* __restrict__ Hb,
                          int* __restrict__ cnt,
                          unsigned short* __restrict__ w2f,
                          int E, int ngeo) {
    const int bid = blockIdx.x;
    if (bid >= ngeo) {
        // ---- conv_w2: w2 -> MFMA B-fragment layout, bf16 ----
        const int layer = bid - ngeo;
        const float* src = w_r2 + (size_t)layer * HID_R * 512;
        unsigned short* dst = w2f + (size_t)layer * 32768;
        for (int idx = threadIdx.x; idx < 32768; idx += 256) {
            int j    = idx & 7;
            int lane = (idx >> 3) & 63;
            int ks   = (idx >> 9) & 1;
            int ct   = idx >> 10;
            int k    = ks * 32 + (lane >> 4) * 8 + j;
            int col  = ct * 16 + (lane & 15);
            dst[idx] = bf16bits(src[k * 512 + col]);
        }
        return;
    }
    const int e = bid * 256 + threadIdx.x;
    if (e >= E) return;
    atomicAdd(&cnt[receivers[e]], 1);
    float ye[16], remb[NRAD];
    geo_core(vectors, e, ye, remb);
    float4* Yd = (float4*)(Y + (size_t)e * 16);
    Yd[0] = make_float4(ye[0], ye[1], ye[2], ye[3]);
    Yd[1] = make_float4(ye[4], ye[5], ye[6], ye[7]);
    Yd[2] = make_float4(ye[8], ye[9], ye[10], ye[11]);
    Yd[3] = make_float4(ye[12], ye[13], ye[14], ye[15]);
    hid_write(remb, w_r1, Hb, e);
}

// ---------- fallback geo ----------
__global__ void geo_kernel(const float* __restrict__ vectors,
                           float* __restrict__ Y, float* __restrict__ Remb, int E) {
    int e = blockIdx.x * 256 + threadIdx.x;
    if (e >= E) return;
    float ye[16], remb[NRAD];
    geo_core(vectors, e, ye, remb);
#pragma unroll
    for (int m = 0; m < 16; m++) Y[(size_t)e * 16 + m] = ye[m];
#pragma unroll
    for (int k = 0; k < NRAD; k++) Remb[(size_t)e * NRAD + k] = remb[k];
}

// ---------- CSR scan / scatter ----------
__global__ void scan_kernel(const int* __restrict__ cnt, int* __restrict__ offs, int N) {
    __shared__ int buf[256];
    __shared__ int carry;
    int t = threadIdx.x;
    if (t == 0) carry = 0;
    __syncthreads();
    for (int base = 0; base < N; base += 256) {
        int v = (base + t < N) ? cnt[base + t] : 0;
        buf[t] = v;
        __syncthreads();
#pragma unroll
        for (int off = 1; off < 256; off <<= 1) {
            int x = (t >= off) ? buf[t - off] : 0;
            __syncthreads();
            buf[t] += x;
            __syncthreads();
        }
        if (base + t < N) offs[base + t] = carry + buf[t] - v;   // exclusive
        __syncthreads();
        if (t == 0) carry += buf[255];
        __syncthreads();
    }
    if (t == 0) offs[N] = carry;
}

__global__ void scatter_kernel(const int* __restrict__ receivers,
                               const int* __restrict__ senders,
                               const int* __restrict__ offs, int* __restrict__ cur,
                               int* __restrict__ eidx, int* __restrict__ snd_csr,
                               int* __restrict__ rcv_csr, int E) {
    int e = blockIdx.x * 256 + threadIdx.x;
    if (e >= E) return;
    int r = receivers[e];
    int pos = atomicAdd(&cur[r], 1);
    int t = offs[r] + pos;
    eidx[t] = e;
    snd_csr[t] = senders[e];
    rcv_csr[t] = r;
}

// ---------- feats init (fallback only) ----------
__global__ void init_feats_kernel(const float* __restrict__ w_embed,
                                  const int* __restrict__ specie,
                                  float* __restrict__ feats_t, int N) {
    int n = blockIdx.x;
    int sp = specie[n];
    for (int i = threadIdx.x; i < F * LDIM; i += 256) {
        int m = i >> 6;
        int f = i & 63;
        feats_t[(size_t)n * (F * LDIM) + i] = (m == 0) ? w_embed[sp * F + f] : 0.0f;
    }
}

// ========== fused edge kernel: MFMA -> fp32 LDS -> prefetched segment reduce ==========
// block = 2 nodes; 16-edge batches. LDS R: addr = el*532 + lc*66 + f (floats) ->
// both MFMA-frag writes and per-(l,c) reads hit <=2 lanes/bank (free, m136).
template <bool L0>
__global__ __launch_bounds__(256, 4)
void fused_edge_kernel(const unsigned short* __restrict__ Hb,
                       const unsigned short* __restrict__ w2fl,
                       const float* __restrict__ Y,
                       const float* __restrict__ feats,
                       const float* __restrict__ w_embed,
                       const int* __restrict__ specie,
                       const int* __restrict__ offs,
                       const int* __restrict__ eidx,
                       const int* __restrict__ snd_csr,
                       const int* __restrict__ rcv_csr,
                       float* __restrict__ agg, int N) {
    __shared__ float R_lds[16 * 532];   // 34,048 B
    __shared__ float ysL[16][16];
    __shared__ int   ssL[16];           // L0: sender specie; L1: sender id
    __shared__ int   rsL[16];
    const int tid = threadIdx.x;
    const int wave = tid >> 6, lane = tid & 63;
    const int lo = lane & 15, hi = lane >> 4;
    const int n0 = blockIdx.x * 2;
    const int segS = offs[n0], segE = offs[n0 + 2];
    const int mbase = wave * 4;

    int cur = -1;
    float acc[4] = {0.f, 0.f, 0.f, 0.f};

    for (int base = segS; base < segE; base += 16) {
        const int bend = (base + 16 < segE) ? base + 16 : segE;
        const int tcnt = bend - base;
        // ---------- phase 0: preload Y rows + metadata ----------
        {
            const int t = tid >> 4, m = tid & 15;
            const int pos = base + t;
            const int cp = (pos < segE) ? pos : (segE - 1);
            ysL[t][m] = Y[(size_t)eidx[cp] * 16 + m];
            if (tid < 16) {
                const int p2 = base + tid;
                const int c2 = (p2 < segE) ? p2 : (segE - 1);
                const int s = snd_csr[c2];
                ssL[tid] = L0 ? specie[s] : s;
                rsL[tid] = rcv_csr[c2];
            }
        }
        // ---------- phase 1: MFMA 16 edges x 512; fp32 -> LDS ----------
        {
            const int pos = base + lo;
            const int cp = (pos < segE) ? pos : (segE - 1);
            const int eid = eidx[cp];
            const unsigned short* hrow = Hb + (size_t)eid * 64;
            const short8v a0 = *(const short8v*)(hrow + hi * 8);
            const short8v a1 = *(const short8v*)(hrow + 32 + hi * 8);
            f32x4 c16[8];
#pragma unroll
            for (int i = 0; i < 8; i++) c16[i] = (f32x4)(0.f);
#pragma unroll
            for (int tt = 0; tt < 8; tt++) {
                const int ct = wave * 8 + tt;
                const short8v b0 = *(const short8v*)(w2fl + ct * 1024 + lane * 8);
                const short8v b1 = *(const short8v*)(w2fl + ct * 1024 + 512 + lane * 8);
                c16[tt] = __builtin_amdgcn_mfma_f32_16x16x32_bf16(a0, b0, c16[tt], 0, 0, 0);
                c16[tt] = __builtin_amdgcn_mfma_f32_16x16x32_bf16(a1, b1, c16[tt], 0, 0, 0);
            }
            const int lc = lo & 7;
#pragma unroll
            for (int tt = 0; tt < 8; tt++) {
                const int ct = wave * 8 + tt;
                const int f = ct * 2 + (lo >> 3);
#pragma unroll
                for (int r = 0; r < 4; r++) {
                    const int el = hi * 4 + r;
                    R_lds[el * 532 + lc * 66 + f] = c16[tt][r];
                }
            }
        }
        __syncthreads();
        // ---------- phase 2: weight + segment reduce, depth-1 prefetch ----------
        {
            float ps0, pf[4] = {0.f, 0.f, 0.f, 0.f};
            if (L0) {
                ps0 = w_embed[ssL[0] * 64 + lane];
            } else {
                const float* f_ = feats + (size_t)ssL[0] * 1024;
                ps0 = f_[lane];
#pragma unroll
                for (int j = 0; j < 4; j++) pf[j] = f_[(mbase + j) * 64 + lane];
            }
            for (int k = 0; k < tcnt; k++) {
                // issue next edge's gather early (hides L2/HBM latency under math)
                float ns0 = 0.f, nf[4] = {0.f, 0.f, 0.f, 0.f};
                const int kn = (k + 1 < tcnt) ? k + 1 : k;
                if (L0) {
                    ns0 = w_embed[ssL[kn] * 64 + lane];
                } else {
                    const float* f_ = feats + (size_t)ssL[kn] * 1024;
                    ns0 = f_[lane];
#pragma unroll
                    for (int j = 0; j < 4; j++) nf[j] = f_[(mbase + j) * 64 + lane];
                }
                // segment boundary
                const int node = rsL[k];
                if (node != cur) {
                    if (cur >= 0) {
#pragma unroll
                        for (int j = 0; j < 4; j++)
                            agg[(size_t)cur * 1024 + (mbase + j) * 64 + lane] = acc[j] * 0.25f;
                    }
#pragma unroll
                    for (int j = 0; j < 4; j++) acc[j] = 0.f;
                    cur = node;
                }
                const float* Rt = R_lds + k * 532;
#pragma unroll
                for (int j = 0; j < 4; j++) {
                    const int m = mbase + j;
                    const int l = l_of_m(m);
                    const float r0 = Rt[(2 * l) * 66 + lane];
                    const float r1 = Rt[(2 * l + 1) * 66 + lane];
                    const float ym = ysL[k][m];
                    const float fsm = L0 ? ((m == 0) ? ps0 : 0.f) : pf[j];
                    acc[j] += r0 * ps0 * ym + r1 * fsm;
                }
                ps0 = ns0;
                if (!L0) {
#pragma unroll
                    for (int j = 0; j < 4; j++) pf[j] = nf[j];
                }
            }
        }
        __syncthreads();
    }
    if (cur >= 0) {
#pragma unroll
        for (int j = 0; j < 4; j++)
            agg[(size_t)cur * 1024 + (mbase + j) * 64 + lane] = acc[j] * 0.25f;
    }
    // zero-degree nodes (agg never memset)
#pragma unroll
    for (int d = 0; d < 2; d++) {
        const int nn = n0 + d;
        if (nn < N && offs[nn] == offs[nn + 1]) {
#pragma unroll
            for (int j = 0; j < 4; j++)
                agg[(size_t)nn * 1024 + (mbase + j) * 64 + lane] = 0.f;
        }
    }
}

// ========== K2: node0 (shfl matvec)  |  geo+H(L1) tail blocks ==========
// NOTE: __builtin_amdgcn_readlane takes uint args — passing float goes through
// float->uint CONVERSION (v_cvt_u32_f32: truncates, clamps negatives to 0),
// silently corrupting the matvec (rounds 6/7 failure). Use __shfl for floats.
__global__ void k2_kernel(const float* __restrict__ agg,
                          const int* __restrict__ specie,
                          const float* __restrict__ w_skip0,
                          const float* __restrict__ w_poly0,
                          const float* __restrict__ w_read0,
                          float* __restrict__ feats,
                          float* __restrict__ out, int N,
                          const float* __restrict__ vectors,
                          const float* __restrict__ w1L1,
                          unsigned short* __restrict__ Hb, int E) {
    if (blockIdx.x >= N) {
        const int e = (blockIdx.x - N) * 256 + threadIdx.x;
        if (e >= E) return;
        float ye[16], remb[NRAD];
        geo_core(vectors, e, ye, remb);
        hid_write(remb, w1L1, Hb, e);
        return;
    }
    const int n = blockIdx.x;
    const int g = threadIdx.x & 63;
    const int mb = threadIdx.x >> 6;
    const int sp = specie[n];
    const float* W = w_skip0 + (size_t)sp * 4 * F * F;

    float areg[4];
#pragma unroll
    for (int j = 0; j < 4; j++) areg[j] = agg[(size_t)n * 1024 + (mb * 4 + j) * 64 + g];

    float h[4] = {0.f, 0.f, 0.f, 0.f};
    if (mb == 0) {            // m0 -> l0 ; m1..3 -> l1
        const float* W0 = W;
        const float* W1 = W + 4096;
#pragma unroll
        for (int f = 0; f < 64; f++) {
            const float w0 = W0[f * 64 + g];
            const float w1 = W1[f * 64 + g];
            h[0] += __shfl(areg[0], f) * w0;
            h[1] += __shfl(areg[1], f) * w1;
            h[2] += __shfl(areg[2], f) * w1;
            h[3] += __shfl(areg[3], f) * w1;
        }
    } else if (mb == 1) {     // m4..7 -> l2
        const float* W2 = W + 8192;
#pragma unroll
        for (int f = 0; f < 64; f++) {
            const float w2 = W2[f * 64 + g];
            h[0] += __shfl(areg[0], f) * w2;
            h[1] += __shfl(areg[1], f) * w2;
            h[2] += __shfl(areg[2], f) * w2;
            h[3] += __shfl(areg[3], f) * w2;
        }
    } else if (mb == 2) {     // m8 -> l2 ; m9..11 -> l3
        const float* W2 = W + 8192;
        const float* W3 = W + 12288;
#pragma unroll
        for (int f = 0; f < 64; f++) {
            const float w2 = W2[f * 64 + g];
            const float w3 = W3[f * 64 + g];
            h[0] += __shfl(areg[0], f) * w2;
            h[1] += __shfl(areg[1], f) * w3;
            h[2] += __shfl(areg[2], f) * w3;
            h[3] += __shfl(areg[3], f) * w3;
        }
    } else {                  // m12..15 -> l3
        const float* W3 = W + 12288;
#pragma unroll
        for (int f = 0; f < 64; f++) {
            const float w3 = W3[f * 64 + g];
            h[0] += __shfl(areg[0], f) * w3;
            h[1] += __shfl(areg[1], f) * w3;
            h[2] += __shfl(areg[2], f) * w3;
            h[3] += __shfl(areg[3], f) * w3;
        }
    }

    __shared__ float h0L[64];
    if (mb == 0) h0L[g] = h[0];
    __syncthreads();
    const float s = h0L[g];
    const float c0 = w_poly0[(0 * NSPEC + sp) * F + g];
    const float c1 = w_poly0[(1 * NSPEC + sp) * F + g];
    const float c2 = w_poly0[(2 * NSPEC + sp) * F + g];
    const float scale = c0 + c1 * s + c2 * s * s;
    float f0val = 0.0f;
#pragma unroll
    for (int j = 0; j < 4; j++) {
        const int m = mb * 4 + j;
        const float fv = h[j] * scale;
        feats[(size_t)n * 1024 + m * 64 + g] = fv;
        if (m == 0) f0val = fv;
    }
    if (mb == 0) {
        float v = f0val * w_read0[g];
#pragma unroll
        for (int off = 32; off > 0; off >>= 1) v += __shfl_down(v, off);
        if (g == 0) out[(size_t)n * 2 + 0] = v;
    }
}

// ---------- node kernel, layer 1 (verified) ----------
__global__ void node1_kernel(const float* __restrict__ agg,
                             const float* __restrict__ feats,
                             const int* __restrict__ specie,
                             const float* __restrict__ w_skip1,
                             const float* __restrict__ w_poly1,
                             const float* __restrict__ w_mlp1,
                             const float* __restrict__ w_mlp2,
                             float* __restrict__ out, int N) {
    const int wave = threadIdx.x >> 6;
    const int lane = threadIdx.x & 63;
    const int n = blockIdx.x * 4 + wave;
    const int sp = specie[n];
    const float* W0 = w_skip1 + (size_t)sp * 4 * F * F;
    const float fv = feats[(size_t)n * 1024 + lane];
    float sc0 = 0.0f;
#pragma unroll 8
    for (int f = 0; f < F; f++) {
        const float ff = __shfl(fv, f);
        sc0 += ff * W0[f * F + lane];
    }
    const float h0 = agg[(size_t)n * 1024 + lane];
    const float c0 = w_poly1[(0 * NSPEC + sp) * F + lane];
    const float c1 = w_poly1[(1 * NSPEC + sp) * F + lane];
    const float c2 = w_poly1[(2 * NSPEC + sp) * F + lane];
    const float scale = c0 + c1 * h0 + c2 * h0 * h0;
    const float f2 = h0 * scale + sc0;
    float acc = 0.0f;
#pragma unroll 8
    for (int gg = 0; gg < F; gg++) {
        const float fg = __shfl(f2, gg);
        if (lane < HID_READ) acc += fg * w_mlp1[gg * HID_READ + lane];
    }
    float o = 0.0f;
    if (lane < HID_READ) o = silu(acc) * w_mlp2[lane];
#pragma unroll
    for (int off = 32; off > 0; off >>= 1) o += __shfl_down(o, off);
    if (lane == 0) out[(size_t)n * 2 + 1] = o;
}

// ---------- fallback (round-1, known-passing) edge kernel ----------
__global__ void edge_kernel(const float* __restrict__ Y, const float* __restrict__ Remb,
                            const float* __restrict__ feats_t,
                            const int* __restrict__ senders, const int* __restrict__ receivers,
                            const float* __restrict__ w1, const float* __restrict__ w2,
                            float* __restrict__ agg_t, int E) {
    const int wave = threadIdx.x >> 6;
    const int lane = threadIdx.x & 63;
    const int e = blockIdx.x * 4 + wave;
    __shared__ float hbuf[4][64];
    const float* remb = Remb + (size_t)e * NRAD;
    float acc = 0.0f;
#pragma unroll
    for (int k = 0; k < NRAD; k++) acc += remb[k] * w1[k * F + lane];
    hbuf[wave][lane] = silu(acc);
    __syncthreads();
    float r8[8] = {0.f, 0.f, 0.f, 0.f, 0.f, 0.f, 0.f, 0.f};
    const float* w2base = w2 + lane * 8;
#pragma unroll 8
    for (int j = 0; j < HID_R; j++) {
        float hj = hbuf[wave][j];
        const float4 a = *(const float4*)(w2base + j * 512);
        const float4 b = *(const float4*)(w2base + j * 512 + 4);
        r8[0] += hj * a.x; r8[1] += hj * a.y; r8[2] += hj * a.z; r8[3] += hj * a.w;
        r8[4] += hj * b.x; r8[5] += hj * b.y; r8[6] += hj * b.z; r8[7] += hj * b.w;
    }
    const int snd = senders[e];
    const int rcv = receivers[e];
    const float* fsrc = feats_t + (size_t)snd * (F * LDIM);
    float* adst = agg_t + (size_t)rcv * (F * LDIM);
    const float s0 = fsrc[lane];
    const float* Ye = Y + (size_t)e * 16;
#pragma unroll
    for (int m = 0; m < LDIM; m++) {
        const int l = l_of_m(m);
        const float ym = Ye[m];
        const float fsm = fsrc[m * F + lane];
        const float val = r8[l * 2 + 0] * s0 * ym + r8[l * 2 + 1] * fsm;
        atomicAdd(adst + m * F + lane, val * 0.25f);
    }
}

static inline size_t alignup(size_t x) { return (x + 255) & ~(size_t)255; }

extern "C" void kernel_launch(void* const* d_in, const int* in_sizes, int n_in,
                              void* d_out, int out_size, void* d_ws, size_t ws_size,
                              hipStream_t stream) {
    const float* vectors   = (const float*)d_in[0];
    const int*   specie    = (const int*)d_in[1];
    const int*   senders   = (const int*)d_in[2];
    const int*   receivers = (const int*)d_in[3];
    const float* w_embed   = (const float*)d_in[4];
    const float* w_r1      = (const float*)d_in[5];
    const float* w_r2      = (const float*)d_in[6];
    const float* w_skip    = (const float*)d_in[7];
    const float* w_poly    = (const float*)d_in[8];
    const float* w_read0   = (const float*)d_in[9];
    const float* w_mlp1    = (const float*)d_in[10];
    const float* w_mlp2    = (const float*)d_in[11];
    float* out = (float*)d_out;

    const int E = in_sizes[0] / 3;   // 160000
    const int N = in_sizes[1];       // 10000
    const int ngeo = (E + 255) / 256;

    // ---- fast-path workspace layout (~115 MB) ----
    char* base = (char*)d_ws;
    size_t off = 0;
    float* Y      = (float*)(base + off); off += alignup((size_t)E * 16 * sizeof(float));
    float* feats  = (float*)(base + off); off += alignup((size_t)N * F * LDIM * sizeof(float));
    float* agg    = (float*)(base + off); off += alignup((size_t)N * F * LDIM * sizeof(float));
    unsigned short* Hb = (unsigned short*)(base + off); off += alignup((size_t)E * 64 * sizeof(unsigned short));
    int* cnt      = (int*)(base + off);   off += alignup((size_t)N * sizeof(int));
    int* cur      = (int*)(base + off);   off += alignup((size_t)N * sizeof(int));
    int* offs     = (int*)(base + off);   off += alignup((size_t)(N + 1) * sizeof(int));
    int* eidx     = (int*)(base + off);   off += alignup((size_t)E * sizeof(int));
    int* snd_csr  = (int*)(base + off);   off += alignup((size_t)E * sizeof(int));
    int* rcv_csr  = (int*)(base + off);   off += alignup((size_t)E * sizeof(int));
    unsigned short* w2f = (unsigned short*)(base + off); off += alignup((size_t)2 * 32768 * sizeof(unsigned short));
    const size_t need = off;

    const size_t aggBytes = (size_t)N * F * LDIM * sizeof(float);

    if (ws_size >= need) {
        // =========== fast path ===========
        hipMemsetAsync(cnt, 0, (size_t)N * sizeof(int), stream);
        hipMemsetAsync(cur, 0, (size_t)N * sizeof(int), stream);
        k1_kernel<<<ngeo + 2, 256, 0, stream>>>(vectors, w_r1, w_r2, receivers,
                                                Y, Hb, cnt, w2f, E, ngeo);
        scan_kernel<<<1, 256, 0, stream>>>(cnt, offs, N);
        scatter_kernel<<<ngeo, 256, 0, stream>>>(receivers, senders, offs, cur,
                                                 eidx, snd_csr, rcv_csr, E);
        // ---- layer 0 ----
        fused_edge_kernel<true><<<N / 2, 256, 0, stream>>>(
            Hb, w2f, Y, nullptr, w_embed, specie, offs, eidx, snd_csr, rcv_csr, agg, N);
        // ---- node0 + geo/H for layer 1 ----
        k2_kernel<<<N + ngeo, 256, 0, stream>>>(agg, specie,
                                                w_skip + (size_t)0 * NSPEC * 4 * F * F,
                                                w_poly + (size_t)0 * 3 * NSPEC * F,
                                                w_read0, feats, out, N,
                                                vectors, w_r1 + NRAD * HID_R, Hb, E);
        // ---- layer 1 ----
        fused_edge_kernel<false><<<N / 2, 256, 0, stream>>>(
            Hb, w2f + 32768, Y, feats, w_embed, specie, offs, eidx, snd_csr, rcv_csr, agg, N);
        node1_kernel<<<N / 4, 256, 0, stream>>>(agg, feats, specie,
                                                w_skip + (size_t)1 * NSPEC * 4 * F * F,
                                                w_poly + (size_t)1 * 3 * NSPEC * F,
                                                w_mlp1, w_mlp2, out, N);
    } else {
        // =========== fallback: round-1 atomic path ===========
        size_t fo = 0;
        float* Yf    = (float*)(base + fo); fo += alignup((size_t)E * 16 * sizeof(float));
        float* Remb  = (float*)(base + fo); fo += alignup((size_t)E * NRAD * sizeof(float));
        float* featsF= (float*)(base + fo); fo += alignup((size_t)N * F * LDIM * sizeof(float));
        float* aggF  = (float*)(base + fo);

        geo_kernel<<<ngeo, 256, 0, stream>>>(vectors, Yf, Remb, E);
        init_feats_kernel<<<N, 256, 0, stream>>>(w_embed, specie, featsF, N);
        hipMemsetAsync(aggF, 0, aggBytes, stream);
        edge_kernel<<<E / 4, 256, 0, stream>>>(Yf, Remb, featsF, senders, receivers,
                                               w_r1, w_r2, aggF, E);
        k2_kernel<<<N, 256, 0, stream>>>(aggF, specie,
                                         w_skip + (size_t)0 * NSPEC * 4 * F * F,
                                         w_poly + (size_t)0 * 3 * NSPEC * F,
                                         w_read0, featsF, out, N,
                                         vectors, w_r1 + NRAD * HID_R, nullptr, 0);
        hipMemsetAsync(aggF, 0, aggBytes, stream);
        edge_kernel<<<E / 4, 256, 0, stream>>>(Yf, Remb, featsF, senders, receivers,
                                               w_r1 + NRAD * HID_R, w_r2 + HID_R * 512,
                                               aggF, E);
        node1_kernel<<<N / 4, 256, 0, stream>>>(aggF, featsF, specie,
                                                w_skip + (size_t)1 * NSPEC * 4 * F * F,
                                                w_poly + (size_t)1 * 3 * NSPEC * F,
                                                w_mlp1, w_mlp2, out, N);
    }
}